// Round 6
// baseline (515.250 us; speedup 1.0000x reference)
//
#include <hip/hip_runtime.h>
#include <math.h>

#define HW 262144     // 512*512
#define NIMG 96       // B*C
#define NQBIN 4096

typedef __attribute__((ext_vector_type(8))) short bf16x8;
typedef __attribute__((ext_vector_type(4))) float f32x4;

// ---- helpers ----
__device__ __forceinline__ unsigned fmap_u(float f){
  unsigned u = __float_as_uint(f);
  return (u & 0x80000000u) ? ~u : (u | 0x80000000u);
}
__device__ __forceinline__ float funmap_u(unsigned u){
  unsigned v = (u & 0x80000000u) ? (u & 0x7fffffffu) : ~u;
  return __uint_as_float(v);
}
__device__ __forceinline__ unsigned bf16rne(float f){
  unsigned u = __float_as_uint(f);
  return (u + 0x7fffu + ((u >> 16) & 1u)) >> 16;
}
__device__ __forceinline__ void split2(float v, unsigned &h, unsigned &l){
  h = bf16rne(v);
  float fh = __uint_as_float(h << 16);
  l = bf16rne(v - fh);
}

// ---- Dir[n] = Re( ifft(filter_map row 0) )[n], computed in double ----
__global__ void k_dir(const float* __restrict__ fmap_in, float* __restrict__ Dir){
  int n = blockIdx.x;
  int t = threadIdx.x;
  double s = 0.0;
  for(int c = t; c < 512; c += 256){
    int a = (c * n) & 511;
    s += (double)fmap_in[c] * cos(6.283185307179586476925287 * (double)a / 512.0);
  }
  __shared__ double red[256];
  red[t] = s; __syncthreads();
  for(int off = 128; off; off >>= 1){
    if(t < off) red[t] += red[t + off];
    __syncthreads();
  }
  if(t == 0) Dir[n] = (float)(red[0] / 512.0);
}

// ---- Cm[a][b] = Dir[(a-b)&511], split bf16 hi/lo (1 MB, L2-resident) ----
__global__ void k_cmat(const float* __restrict__ Dir, unsigned short* __restrict__ CmH,
                       unsigned short* __restrict__ CmL){
  int a = blockIdx.x;
  for(int b = threadIdx.x; b < 512; b += 256){
    float d = Dir[(a - b) & 511];
    unsigned h, l; split2(d, h, l);
    CmH[(size_t)a * 512 + b] = (unsigned short)h;
    CmL[(size_t)a * 512 + b] = (unsigned short)l;
  }
}

// ==== exact-to-24-bits median via 2-pass LDS radix select (12 / 12 bits) ====
__global__ __launch_bounds__(256) void k_p1(const float* __restrict__ x, unsigned* __restrict__ h){
  __shared__ unsigned sh[4096];
  const int img  = blockIdx.x >> 3;
  const int part = blockIdx.x & 7;
  const float4* p = (const float4*)(x + (size_t)img * HW + (size_t)part * 32768);
  for(int i = threadIdx.x; i < 4096; i += 256) sh[i] = 0;
  __syncthreads();
  for(int i = threadIdx.x; i < 8192; i += 256){
    float4 v = p[i];
    atomicAdd(&sh[fmap_u(v.x) >> 20], 1u);
    atomicAdd(&sh[fmap_u(v.y) >> 20], 1u);
    atomicAdd(&sh[fmap_u(v.z) >> 20], 1u);
    atomicAdd(&sh[fmap_u(v.w) >> 20], 1u);
  }
  __syncthreads();
  unsigned* hh = h + (size_t)img * 4096;
  for(int i = threadIdx.x; i < 4096; i += 256){
    unsigned c = sh[i];
    if(c) atomicAdd(&hh[i], c);
  }
}

__global__ __launch_bounds__(256) void k_p2(const float* __restrict__ x, const uint2* __restrict__ sel1,
                                            unsigned* __restrict__ h){
  __shared__ unsigned sh[4096];
  const int img  = blockIdx.x >> 3;
  const int part = blockIdx.x & 7;
  const unsigned b1 = sel1[img].x;
  const float4* p = (const float4*)(x + (size_t)img * HW + (size_t)part * 32768);
  for(int i = threadIdx.x; i < 4096; i += 256) sh[i] = 0;
  __syncthreads();
  for(int i = threadIdx.x; i < 8192; i += 256){
    float4 v = p[i];
    unsigned u;
    u = fmap_u(v.x); if((u >> 20) == b1) atomicAdd(&sh[(u >> 8) & 0xFFFu], 1u);
    u = fmap_u(v.y); if((u >> 20) == b1) atomicAdd(&sh[(u >> 8) & 0xFFFu], 1u);
    u = fmap_u(v.z); if((u >> 20) == b1) atomicAdd(&sh[(u >> 8) & 0xFFFu], 1u);
    u = fmap_u(v.w); if((u >> 20) == b1) atomicAdd(&sh[(u >> 8) & 0xFFFu], 1u);
  }
  __syncthreads();
  unsigned* hh = h + (size_t)img * 4096;
  for(int i = threadIdx.x; i < 4096; i += 256){
    unsigned c = sh[i];
    if(c) atomicAdd(&hh[i], c);
  }
}

// pass-1 scan: find 12-bit bin containing rank 131071; (bin, residual rank)
__global__ void k_scan1(const unsigned* __restrict__ h, uint2* __restrict__ osel){
  int img = blockIdx.x, t = threadIdx.x;
  const unsigned* hh = h + (size_t)img * 4096;
  __shared__ unsigned csum[256];
  unsigned s = 0;
  for(int j = 0; j < 16; j++) s += hh[t * 16 + j];
  csum[t] = s; __syncthreads();
  if(t == 0){
    unsigned k = 131071u, cum = 0; int chunk = 0;
    for(; chunk < 256; ++chunk){ if(cum + csum[chunk] > k) break; cum += csum[chunk]; }
    int b = chunk * 16;
    for(;; ++b){ unsigned c = hh[b]; if(cum + c > k) break; cum += c; }
    osel[img] = make_uint2((unsigned)b, k - cum);
  }
}

// pass-2 scan: 24-bit prefix known; emit median = prefix-bin midpoint (+0.2)
__global__ void k_scan_med(const unsigned* __restrict__ h, const uint2* __restrict__ sel1,
                           float* __restrict__ med){
  int img = blockIdx.x, t = threadIdx.x;
  const unsigned* hh = h + (size_t)img * 4096;
  __shared__ unsigned csum[256];
  unsigned s = 0;
  for(int j = 0; j < 16; j++) s += hh[t * 16 + j];
  csum[t] = s; __syncthreads();
  if(t == 0){
    unsigned k = sel1[img].y, cum = 0; int chunk = 0;
    for(; chunk < 256; ++chunk){ if(cum + csum[chunk] > k) break; cum += csum[chunk]; }
    int b = chunk * 16;
    for(;; ++b){ unsigned c = hh[b]; if(cum + c > k) break; cum += c; }
    unsigned u = (sel1[img].x << 20) | ((unsigned)b << 8) | 128u;
    med[img] = funmap_u(u) + 0.2f;
  }
}

// ==== MFMA row pass (software-pipelined, T14 async-STAGE split) ====
// t1T[img][n][h] = bf16( sum_k padded[r][k] * Cm[n][k] )
__global__ __launch_bounds__(256, 3) void k_rowpass(
    const float* __restrict__ x, const float* __restrict__ mask,
    const float* __restrict__ med,
    const unsigned short* __restrict__ CmH, const unsigned short* __restrict__ CmL,
    unsigned short* __restrict__ t1h)
{
  __shared__ __align__(16) unsigned short AsH[128][40];
  __shared__ __align__(16) unsigned short BsH[128][40];
  __shared__ __align__(16) unsigned short BsL[128][40];

  // XCD swizzle: 4 sibling n-blocks (same rows) on the same XCD
  const int b    = blockIdx.x;           // 0..1535
  const int xcd  = b & 7;
  const int i8   = b >> 3;               // 0..191
  const int rblk = xcd * 48 + (i8 >> 2); // 0..383
  const int nblk = i8 & 3;
  const int r0 = rblk * 128;
  const int n0 = nblk * 128;
  const int bc = r0 >> 9;
  const int bb = bc / 3;
  const float mv = med[bc];

  const int t    = threadIdx.x;
  const int lane = t & 63;
  const int wv   = t >> 6;
  const int wm   = (wv >> 1) * 64;
  const int wn   = (wv & 1) * 64;
  const int fr   = lane & 15;
  const int fg   = lane >> 4;

  f32x4 acc[4][4];
  #pragma unroll
  for(int i = 0; i < 4; i++)
    #pragma unroll
    for(int j = 0; j < 4; j++) acc[i][j] = (f32x4){0.f, 0.f, 0.f, 0.f};

  const int sm = t >> 1;             // staging row 0..127
  const int kc = (t & 1) << 4;       // 0 or 16

  const float*          xr0 = x    + ((size_t)(r0 + sm) << 9) + kc;
  const float*          mr0 = mask + (size_t)bb * HW + ((size_t)((r0 + sm) & 511) << 9) + kc;
  const unsigned short* bh0 = CmH  + ((size_t)(n0 + sm) << 9) + kc;
  const unsigned short* bl0 = CmL  + ((size_t)(n0 + sm) << 9) + kc;

  float4 px[4], pm[4];
  uint4  pbh[2], pbl[2];

  // prologue: load tile 0
  #pragma unroll
  for(int q = 0; q < 4; q++){ px[q] = *(const float4*)(xr0 + q*4); pm[q] = *(const float4*)(mr0 + q*4); }
  pbh[0] = *(const uint4*)(bh0);     pbh[1] = *(const uint4*)(bh0 + 8);
  pbl[0] = *(const uint4*)(bl0);     pbl[1] = *(const uint4*)(bl0 + 8);

  for(int it = 0; it < 16; ++it){
    // --- write staged regs -> LDS (mask-select + bf16 convert here) ---
    {
      unsigned hp[8];
      #pragma unroll
      for(int q = 0; q < 4; q++){
        unsigned h0 = bf16rne((pm[q].x != 0.f) ? px[q].x : mv);
        unsigned h1 = bf16rne((pm[q].y != 0.f) ? px[q].y : mv);
        unsigned h2 = bf16rne((pm[q].z != 0.f) ? px[q].z : mv);
        unsigned h3 = bf16rne((pm[q].w != 0.f) ? px[q].w : mv);
        hp[q*2]   = (h1 << 16) | h0;
        hp[q*2+1] = (h3 << 16) | h2;
      }
      *(uint4*)&AsH[sm][kc]     = make_uint4(hp[0], hp[1], hp[2], hp[3]);
      *(uint4*)&AsH[sm][kc + 8] = make_uint4(hp[4], hp[5], hp[6], hp[7]);
      *(uint4*)&BsH[sm][kc]     = pbh[0];
      *(uint4*)&BsH[sm][kc + 8] = pbh[1];
      *(uint4*)&BsL[sm][kc]     = pbl[0];
      *(uint4*)&BsL[sm][kc + 8] = pbl[1];
    }
    __syncthreads();

    // --- issue next tile's global loads (latency hides under MFMA below) ---
    if(it < 15){
      const int ko = (it + 1) * 32;
      #pragma unroll
      for(int q = 0; q < 4; q++){
        px[q] = *(const float4*)(xr0 + ko + q*4);
        pm[q] = *(const float4*)(mr0 + ko + q*4);
      }
      pbh[0] = *(const uint4*)(bh0 + ko);  pbh[1] = *(const uint4*)(bh0 + ko + 8);
      pbl[0] = *(const uint4*)(bl0 + ko);  pbl[1] = *(const uint4*)(bl0 + ko + 8);
    }

    // --- compute current tile from LDS ---
    bf16x8 ah[4], bh[4], bl[4];
    #pragma unroll
    for(int i = 0; i < 4; i++)
      ah[i] = *(const bf16x8*)&AsH[wm + i*16 + fr][fg*8];
    #pragma unroll
    for(int j = 0; j < 4; j++){
      bh[j] = *(const bf16x8*)&BsH[wn + j*16 + fr][fg*8];
      bl[j] = *(const bf16x8*)&BsL[wn + j*16 + fr][fg*8];
    }
    #pragma unroll
    for(int i = 0; i < 4; i++)
      #pragma unroll
      for(int j = 0; j < 4; j++){
        acc[i][j] = __builtin_amdgcn_mfma_f32_16x16x32_bf16(ah[i], bh[j], acc[i][j], 0, 0, 0);
        acc[i][j] = __builtin_amdgcn_mfma_f32_16x16x32_bf16(ah[i], bl[j], acc[i][j], 0, 0, 0);
      }
    __syncthreads();
  }

  // --- store t1 transposed as single bf16: t1T[img][n][h] ---
  const int img = r0 >> 9;
  const int hb  = r0 & 511;
  #pragma unroll
  for(int i = 0; i < 4; i++)
    #pragma unroll
    for(int j = 0; j < 4; j++){
      f32x4 a = acc[i][j];
      unsigned b0 = bf16rne(a[0]), b1 = bf16rne(a[1]), b2 = bf16rne(a[2]), b3 = bf16rne(a[3]);
      int n = n0 + wn + j*16 + fr;
      int h = hb + wm + i*16 + fg*4;
      *(uint2*)&t1h[(size_t)img * HW + ((size_t)n << 9) + h] =
          make_uint2((b1<<16)|b0, (b3<<16)|b2);
    }
}

// ==== MFMA col pass (software-pipelined) + fused q-histogram ====
__global__ __launch_bounds__(256, 3) void k_colpass(
    const unsigned short* __restrict__ t1h,
    const unsigned short* __restrict__ CmH, const unsigned short* __restrict__ CmL,
    float* __restrict__ res, unsigned* __restrict__ qh)
{
  __shared__ __align__(16) unsigned short SH[3 * 128 * 40];   // 30720 B
  unsigned short (*AsH)[40] = (unsigned short(*)[40])SH;
  unsigned short (*AsL)[40] = (unsigned short(*)[40])(SH + 128 * 40);
  unsigned short (*Bs)[40]  = (unsigned short(*)[40])(SH + 2 * 128 * 40);

  // XCD swizzle: all 16 blocks of one image on the same XCD
  const int b    = blockIdx.x;           // 0..1535
  const int xcd  = b & 7;
  const int i8   = b >> 3;               // 0..191
  const int img  = xcd * 12 + (i8 >> 4);
  const int r16  = i8 & 15;
  const int hp0  = (r16 >> 2) * 128;
  const int w0   = (r16 & 3) * 128;

  const int t    = threadIdx.x;
  const int lane = t & 63;
  const int wv   = t >> 6;
  const int wm   = (wv >> 1) * 64;
  const int wn   = (wv & 1) * 64;
  const int fr   = lane & 15;
  const int fg   = lane >> 4;

  f32x4 acc[4][4];
  #pragma unroll
  for(int i = 0; i < 4; i++)
    #pragma unroll
    for(int j = 0; j < 4; j++) acc[i][j] = (f32x4){0.f, 0.f, 0.f, 0.f};

  const int sm = t >> 1;
  const int kc = (t & 1) << 4;

  const unsigned short* ah0 = CmH + ((size_t)(hp0 + sm) << 9) + kc;
  const unsigned short* al0 = CmL + ((size_t)(hp0 + sm) << 9) + kc;
  const unsigned short* tb0 = t1h + (size_t)img * HW + ((size_t)(w0 + sm) << 9) + kc;

  uint4 pah[2], pal[2], pb[2];

  // prologue: load tile 0
  pah[0] = *(const uint4*)(ah0);     pah[1] = *(const uint4*)(ah0 + 8);
  pal[0] = *(const uint4*)(al0);     pal[1] = *(const uint4*)(al0 + 8);
  pb[0]  = *(const uint4*)(tb0);     pb[1]  = *(const uint4*)(tb0 + 8);

  for(int it = 0; it < 16; ++it){
    // --- write staged regs -> LDS ---
    *(uint4*)&AsH[sm][kc]     = pah[0];
    *(uint4*)&AsH[sm][kc + 8] = pah[1];
    *(uint4*)&AsL[sm][kc]     = pal[0];
    *(uint4*)&AsL[sm][kc + 8] = pal[1];
    *(uint4*)&Bs[sm][kc]      = pb[0];
    *(uint4*)&Bs[sm][kc + 8]  = pb[1];
    __syncthreads();

    // --- issue next tile's loads ---
    if(it < 15){
      const int ko = (it + 1) * 32;
      pah[0] = *(const uint4*)(ah0 + ko);  pah[1] = *(const uint4*)(ah0 + ko + 8);
      pal[0] = *(const uint4*)(al0 + ko);  pal[1] = *(const uint4*)(al0 + ko + 8);
      pb[0]  = *(const uint4*)(tb0 + ko);  pb[1]  = *(const uint4*)(tb0 + ko + 8);
    }

    // --- compute ---
    bf16x8 ah[4], al[4], bv[4];
    #pragma unroll
    for(int i = 0; i < 4; i++){
      ah[i] = *(const bf16x8*)&AsH[wm + i*16 + fr][fg*8];
      al[i] = *(const bf16x8*)&AsL[wm + i*16 + fr][fg*8];
    }
    #pragma unroll
    for(int j = 0; j < 4; j++)
      bv[j] = *(const bf16x8*)&Bs[wn + j*16 + fr][fg*8];

    #pragma unroll
    for(int i = 0; i < 4; i++)
      #pragma unroll
      for(int j = 0; j < 4; j++){
        acc[i][j] = __builtin_amdgcn_mfma_f32_16x16x32_bf16(ah[i], bv[j], acc[i][j], 0, 0, 0);
        acc[i][j] = __builtin_amdgcn_mfma_f32_16x16x32_bf16(al[i], bv[j], acc[i][j], 0, 0, 0);
      }
    __syncthreads();
  }

  // --- epilogue: store |acc| and histogram it in LDS (reuse tile buffer) ---
  unsigned* shh = (unsigned*)SH;          // 4096 bins = 16 KB <= 30720 B
  for(int i = t; i < NQBIN; i += 256) shh[i] = 0;
  __syncthreads();

  float* rimg = res + (size_t)img * HW;
  #pragma unroll
  for(int i = 0; i < 4; i++)
    #pragma unroll
    for(int j = 0; j < 4; j++){
      f32x4 a = acc[i][j];
      int w  = w0 + wn + j*16 + fr;
      int hp = hp0 + wm + i*16 + fg*4;
      #pragma unroll
      for(int r = 0; r < 4; r++){
        float v = fabsf(a[r]);
        rimg[((size_t)(hp + r) << 9) + w] = v;
        atomicAdd(&shh[min((int)(v * 256.f), NQBIN - 1)], 1u);
      }
    }
  __syncthreads();

  unsigned* hg = qh + (size_t)img * NQBIN;
  for(int i = t; i < NQBIN; i += 256){
    unsigned c = shh[i];
    if(c) atomicAdd(&hg[i], c);
  }
}

// ---- percentiles (linear interp at 3% / 97%) -> (lo, 1/(hi-lo)) ----
__global__ void k_pct(const unsigned* __restrict__ qh, float2* __restrict__ prm){
  int img = blockIdx.x, t = threadIdx.x;
  const unsigned* h = qh + (size_t)img * NQBIN;
  __shared__ unsigned sh[NQBIN];
  for(int i = t; i < NQBIN; i += 256) sh[i] = h[i];
  __syncthreads();
  if(t == 0){
    const unsigned targ[4] = {7864u, 7865u, 254278u, 254279u};
    float v[4]; unsigned cum = 0; int b = 0;
    for(int q = 0; q < 4; q++){
      while(cum + sh[b] <= targ[q]){ cum += sh[b]; ++b; }
      v[q] = (float)b * (1.0f / 256.0f);
    }
    double plo = 0.03 * 262143.0;
    double phi = 0.97 * 262143.0;
    float lo = v[0] + (float)(plo - 7864.0)   * (v[1] - v[0]);
    float hi = v[2] + (float)(phi - 254278.0) * (v[3] - v[2]);
    prm[img] = make_float2(lo, 1.0f / (hi - lo));
  }
}

// ---- in-place normalize: out = (res - lo) * inv * mask ----
__global__ __launch_bounds__(256) void k_norm(float* __restrict__ out, const float* __restrict__ mask,
                                              const float2* __restrict__ prm){
  size_t i4 = (size_t)blockIdx.x * blockDim.x + threadIdx.x;
  const size_t total4 = (size_t)NIMG * HW / 4;
  const size_t step = (size_t)gridDim.x * blockDim.x;
  for(; i4 < total4; i4 += step){
    size_t i = i4 * 4;
    int bc = (int)(i >> 18);
    int bb = bc / 3;
    size_t mi = ((size_t)bb << 18) + (i & 0x3FFFFu);
    float4 r = *(float4*)(out + i);
    float4 m = *(const float4*)(mask + mi);
    float2 p = prm[bc];
    float4 o;
    o.x = (r.x - p.x) * p.y * m.x;
    o.y = (r.y - p.x) * p.y * m.y;
    o.z = (r.z - p.x) * p.y * m.z;
    o.w = (r.w - p.x) * p.y * m.w;
    *(float4*)(out + i) = o;
  }
}

extern "C" void kernel_launch(void* const* d_in, const int* in_sizes, int n_in,
                              void* d_out, int out_size, void* d_ws, size_t ws_size,
                              hipStream_t stream)
{
  const float* x       = (const float*)d_in[0];
  const float* mask    = (const float*)d_in[1];
  const float* fmap_in = (const float*)d_in[2];
  float* out = (float*)d_out;

  const size_t T1_BYTES = (size_t)NIMG * HW * 2;   // 50,331,648 (bf16 t1T)
  char* ws = (char*)d_ws;
  unsigned short* t1h = (unsigned short*)ws;        // lives rowpass..colpass
  // radix histograms alias the (not-yet-written) t1 region:
  unsigned* h1 = (unsigned*)ws;                                        // 1.5 MB
  unsigned* h2 = (unsigned*)(ws + (size_t)NIMG * 4096 * 4);            // 1.5 MB
  char* tail = ws + T1_BYTES;
  float*          Dir = (float*)tail;                                  // 2048 B
  unsigned short* CmH = (unsigned short*)(tail + 2048);                // 512 KB
  unsigned short* CmL = (unsigned short*)(tail + 2048 + 524288);       // 512 KB
  char* tail2 = tail + 2048 + 1048576;
  float*  med  = (float*)tail2;                     // 512 B slot
  uint2*  sel1 = (uint2*)(tail2 + 512);             // 768 B
  float2* prm  = (float2*)(tail2 + 1536);           // 768 B
  unsigned* qh = (unsigned*)(tail2 + 2560);         // 96*4096*4 = 1.5 MB (NOT aliased with t1h)

  k_dir<<<512, 256, 0, stream>>>(fmap_in, Dir);
  k_cmat<<<512, 256, 0, stream>>>(Dir, CmH, CmL);

  // 2-pass LDS radix select: median prefix to 24 bits (midpoint, err <= 8e-6)
  hipMemsetAsync(h1, 0, (size_t)NIMG * 4096 * 4 * 2, stream);
  k_p1<<<NIMG * 8, 256, 0, stream>>>(x, h1);
  k_scan1<<<NIMG, 256, 0, stream>>>(h1, sel1);
  k_p2<<<NIMG * 8, 256, 0, stream>>>(x, sel1, h2);
  k_scan_med<<<NIMG, 256, 0, stream>>>(h2, sel1, med);

  hipMemsetAsync(qh, 0, (size_t)NIMG * NQBIN * 4, stream);
  k_rowpass<<<1536, 256, 0, stream>>>(x, mask, med, CmH, CmL, t1h);
  k_colpass<<<1536, 256, 0, stream>>>(t1h, CmH, CmL, out, qh);

  k_pct<<<NIMG, 256, 0, stream>>>(qh, prm);
  k_norm<<<2048, 256, 0, stream>>>(out, mask, prm);
}

// Round 7
// 421.662 us; speedup vs baseline: 1.2219x; 1.2219x over previous
//
#include <hip/hip_runtime.h>
#include <math.h>

#define HW 262144     // 512*512
#define NIMG 96       // B*C
#define NQBIN 4096

typedef __attribute__((ext_vector_type(8))) short bf16x8;
typedef __attribute__((ext_vector_type(4))) float f32x4;

// ---- helpers ----
__device__ __forceinline__ unsigned fmap_u(float f){
  unsigned u = __float_as_uint(f);
  return (u & 0x80000000u) ? ~u : (u | 0x80000000u);
}
__device__ __forceinline__ float funmap_u(unsigned u){
  unsigned v = (u & 0x80000000u) ? (u & 0x7fffffffu) : ~u;
  return __uint_as_float(v);
}
__device__ __forceinline__ unsigned bf16rne(float f){
  unsigned u = __float_as_uint(f);
  return (u + 0x7fffu + ((u >> 16) & 1u)) >> 16;
}
__device__ __forceinline__ void split2(float v, unsigned &h, unsigned &l){
  h = bf16rne(v);
  float fh = __uint_as_float(h << 16);
  l = bf16rne(v - fh);
}

// ---- Dir[n] = Re( ifft(filter_map row 0) )[n], computed in double ----
__global__ void k_dir(const float* __restrict__ fmap_in, float* __restrict__ Dir){
  int n = blockIdx.x;
  int t = threadIdx.x;
  double s = 0.0;
  for(int c = t; c < 512; c += 256){
    int a = (c * n) & 511;
    s += (double)fmap_in[c] * cos(6.283185307179586476925287 * (double)a / 512.0);
  }
  __shared__ double red[256];
  red[t] = s; __syncthreads();
  for(int off = 128; off; off >>= 1){
    if(t < off) red[t] += red[t + off];
    __syncthreads();
  }
  if(t == 0) Dir[n] = (float)(red[0] / 512.0);
}

// ---- Cm[a][b] = Dir[(a-b)&511], split bf16 hi/lo (1 MB, L2-resident) ----
__global__ void k_cmat(const float* __restrict__ Dir, unsigned short* __restrict__ CmH,
                       unsigned short* __restrict__ CmL){
  int a = blockIdx.x;
  for(int b = threadIdx.x; b < 512; b += 256){
    float d = Dir[(a - b) & 511];
    unsigned h, l; split2(d, h, l);
    CmH[(size_t)a * 512 + b] = (unsigned short)h;
    CmL[(size_t)a * 512 + b] = (unsigned short)l;
  }
}

// ==== exact-to-24-bits median via 2-pass LDS radix select (12 / 12 bits) ====
__global__ __launch_bounds__(256) void k_p1(const float* __restrict__ x, unsigned* __restrict__ h){
  __shared__ unsigned sh[4096];
  const int img  = blockIdx.x >> 3;
  const int part = blockIdx.x & 7;
  const float4* p = (const float4*)(x + (size_t)img * HW + (size_t)part * 32768);
  for(int i = threadIdx.x; i < 4096; i += 256) sh[i] = 0;
  __syncthreads();
  for(int i = threadIdx.x; i < 8192; i += 256){
    float4 v = p[i];
    atomicAdd(&sh[fmap_u(v.x) >> 20], 1u);
    atomicAdd(&sh[fmap_u(v.y) >> 20], 1u);
    atomicAdd(&sh[fmap_u(v.z) >> 20], 1u);
    atomicAdd(&sh[fmap_u(v.w) >> 20], 1u);
  }
  __syncthreads();
  unsigned* hh = h + (size_t)img * 4096;
  for(int i = threadIdx.x; i < 4096; i += 256){
    unsigned c = sh[i];
    if(c) atomicAdd(&hh[i], c);
  }
}

__global__ __launch_bounds__(256) void k_p2(const float* __restrict__ x, const uint2* __restrict__ sel1,
                                            unsigned* __restrict__ h){
  __shared__ unsigned sh[4096];
  const int img  = blockIdx.x >> 3;
  const int part = blockIdx.x & 7;
  const unsigned b1 = sel1[img].x;
  const float4* p = (const float4*)(x + (size_t)img * HW + (size_t)part * 32768);
  for(int i = threadIdx.x; i < 4096; i += 256) sh[i] = 0;
  __syncthreads();
  for(int i = threadIdx.x; i < 8192; i += 256){
    float4 v = p[i];
    unsigned u;
    u = fmap_u(v.x); if((u >> 20) == b1) atomicAdd(&sh[(u >> 8) & 0xFFFu], 1u);
    u = fmap_u(v.y); if((u >> 20) == b1) atomicAdd(&sh[(u >> 8) & 0xFFFu], 1u);
    u = fmap_u(v.z); if((u >> 20) == b1) atomicAdd(&sh[(u >> 8) & 0xFFFu], 1u);
    u = fmap_u(v.w); if((u >> 20) == b1) atomicAdd(&sh[(u >> 8) & 0xFFFu], 1u);
  }
  __syncthreads();
  unsigned* hh = h + (size_t)img * 4096;
  for(int i = threadIdx.x; i < 4096; i += 256){
    unsigned c = sh[i];
    if(c) atomicAdd(&hh[i], c);
  }
}

// pass-1 scan: find 12-bit bin containing rank 131071; (bin, residual rank)
__global__ void k_scan1(const unsigned* __restrict__ h, uint2* __restrict__ osel){
  int img = blockIdx.x, t = threadIdx.x;
  const unsigned* hh = h + (size_t)img * 4096;
  __shared__ unsigned csum[256];
  unsigned s = 0;
  for(int j = 0; j < 16; j++) s += hh[t * 16 + j];
  csum[t] = s; __syncthreads();
  if(t == 0){
    unsigned k = 131071u, cum = 0; int chunk = 0;
    for(; chunk < 256; ++chunk){ if(cum + csum[chunk] > k) break; cum += csum[chunk]; }
    int b = chunk * 16;
    for(;; ++b){ unsigned c = hh[b]; if(cum + c > k) break; cum += c; }
    osel[img] = make_uint2((unsigned)b, k - cum);
  }
}

// pass-2 scan: 24-bit prefix known; emit median = prefix-bin midpoint (+0.2)
__global__ void k_scan_med(const unsigned* __restrict__ h, const uint2* __restrict__ sel1,
                           float* __restrict__ med){
  int img = blockIdx.x, t = threadIdx.x;
  const unsigned* hh = h + (size_t)img * 4096;
  __shared__ unsigned csum[256];
  unsigned s = 0;
  for(int j = 0; j < 16; j++) s += hh[t * 16 + j];
  csum[t] = s; __syncthreads();
  if(t == 0){
    unsigned k = sel1[img].y, cum = 0; int chunk = 0;
    for(; chunk < 256; ++chunk){ if(cum + csum[chunk] > k) break; cum += csum[chunk]; }
    int b = chunk * 16;
    for(;; ++b){ unsigned c = hh[b]; if(cum + c > k) break; cum += c; }
    unsigned u = (sel1[img].x << 20) | ((unsigned)b << 8) | 128u;
    med[img] = funmap_u(u) + 0.2f;
  }
}

// ==== MFMA row pass: A via double-buffered LDS (1 barrier/step), B direct from L2 ====
// t1T[img][n][h] = bf16( sum_k padded[r][k] * Cm[n][k] )
__global__ __launch_bounds__(256, 3) void k_rowpass(
    const float* __restrict__ x, const float* __restrict__ mask,
    const float* __restrict__ med,
    const unsigned short* __restrict__ CmH, const unsigned short* __restrict__ CmL,
    unsigned short* __restrict__ t1h)
{
  __shared__ __align__(16) unsigned short AsH[2][128][40];   // 20 KB

  // XCD swizzle: 4 sibling n-blocks (same rows) on the same XCD
  const int b    = blockIdx.x;           // 0..1535
  const int xcd  = b & 7;
  const int i8   = b >> 3;               // 0..191
  const int rblk = xcd * 48 + (i8 >> 2); // 0..383
  const int nblk = i8 & 3;
  const int r0 = rblk * 128;
  const int n0 = nblk * 128;
  const int bc = r0 >> 9;
  const int bb = bc / 3;
  const float mv = med[bc];

  const int t    = threadIdx.x;
  const int lane = t & 63;
  const int wv   = t >> 6;
  const int wm   = (wv >> 1) * 64;
  const int wn   = (wv & 1) * 64;
  const int fr   = lane & 15;
  const int fg   = lane >> 4;

  f32x4 acc[4][4];
  #pragma unroll
  for(int i = 0; i < 4; i++)
    #pragma unroll
    for(int j = 0; j < 4; j++) acc[i][j] = (f32x4){0.f, 0.f, 0.f, 0.f};

  const int sm = t >> 1;             // staging row 0..127
  const int kc = (t & 1) << 4;       // 0 or 16

  const float* xr0 = x    + ((size_t)(r0 + sm) << 9) + kc;
  const float* mr0 = mask + (size_t)bb * HW + ((size_t)((r0 + sm) & 511) << 9) + kc;
  // per-lane B fragment base (row = n0+wn+fr, k-offset = fg*8)
  const unsigned short* bhp = CmH + ((size_t)(n0 + wn + fr) << 9) + fg * 8;
  const unsigned short* blp = CmL + ((size_t)(n0 + wn + fr) << 9) + fg * 8;

  for(int it = 0; it < 16; ++it){
    const int k0  = it * 32;
    const int buf = it & 1;
    // --- stage A: load, mask-select, convert, write LDS (all within segment) ---
    {
      unsigned hp[8];
      #pragma unroll
      for(int q = 0; q < 4; q++){
        float4 xv = *(const float4*)(xr0 + k0 + q * 4);
        float4 mk = *(const float4*)(mr0 + k0 + q * 4);
        unsigned h0 = bf16rne((mk.x != 0.f) ? xv.x : mv);
        unsigned h1 = bf16rne((mk.y != 0.f) ? xv.y : mv);
        unsigned h2 = bf16rne((mk.z != 0.f) ? xv.z : mv);
        unsigned h3 = bf16rne((mk.w != 0.f) ? xv.w : mv);
        hp[q*2]   = (h1 << 16) | h0;
        hp[q*2+1] = (h3 << 16) | h2;
      }
      *(uint4*)&AsH[buf][sm][kc]     = make_uint4(hp[0], hp[1], hp[2], hp[3]);
      *(uint4*)&AsH[buf][sm][kc + 8] = make_uint4(hp[4], hp[5], hp[6], hp[7]);
    }
    __syncthreads();   // single barrier per step (double buffer)

    // --- B fragments direct from global (L2-resident Cm) ---
    bf16x8 ah[4], bh[4], bl[4];
    #pragma unroll
    for(int j = 0; j < 4; j++){
      bh[j] = *(const bf16x8*)(bhp + j * 8192 + k0);
      bl[j] = *(const bf16x8*)(blp + j * 8192 + k0);
    }
    #pragma unroll
    for(int i = 0; i < 4; i++)
      ah[i] = *(const bf16x8*)&AsH[buf][wm + i*16 + fr][fg*8];

    #pragma unroll
    for(int i = 0; i < 4; i++)
      #pragma unroll
      for(int j = 0; j < 4; j++){
        acc[i][j] = __builtin_amdgcn_mfma_f32_16x16x32_bf16(ah[i], bh[j], acc[i][j], 0, 0, 0);
        acc[i][j] = __builtin_amdgcn_mfma_f32_16x16x32_bf16(ah[i], bl[j], acc[i][j], 0, 0, 0);
      }
    // no trailing barrier: next iter writes the other buffer
  }

  // --- store t1 transposed as single bf16: t1T[img][n][h] ---
  const int img = r0 >> 9;
  const int hb  = r0 & 511;
  #pragma unroll
  for(int i = 0; i < 4; i++)
    #pragma unroll
    for(int j = 0; j < 4; j++){
      f32x4 a = acc[i][j];
      unsigned b0 = bf16rne(a[0]), b1 = bf16rne(a[1]), b2 = bf16rne(a[2]), b3 = bf16rne(a[3]);
      int n = n0 + wn + j*16 + fr;
      int h = hb + wm + i*16 + fg*4;
      *(uint2*)&t1h[(size_t)img * HW + ((size_t)n << 9) + h] =
          make_uint2((b1<<16)|b0, (b3<<16)|b2);
    }
}

// ==== MFMA col pass: all operands direct from L2, no K-loop barriers ====
// res[img][h'][w] = | sum_h Cm[h'][h] * t1T[img][w][h] | ; fused q-histogram
__global__ __launch_bounds__(256, 3) void k_colpass(
    const unsigned short* __restrict__ t1h,
    const unsigned short* __restrict__ CmH, const unsigned short* __restrict__ CmL,
    float* __restrict__ res, unsigned* __restrict__ qh)
{
  __shared__ unsigned shh[NQBIN];   // 16 KB, histogram only

  // XCD swizzle: all 16 blocks of one image on the same XCD (t1 image L2-resident)
  const int b    = blockIdx.x;           // 0..1535
  const int xcd  = b & 7;
  const int i8   = b >> 3;               // 0..191
  const int img  = xcd * 12 + (i8 >> 4);
  const int r16  = i8 & 15;
  const int hp0  = (r16 >> 2) * 128;
  const int w0   = (r16 & 3) * 128;

  const int t    = threadIdx.x;
  const int lane = t & 63;
  const int wv   = t >> 6;
  const int wm   = (wv >> 1) * 64;
  const int wn   = (wv & 1) * 64;
  const int fr   = lane & 15;
  const int fg   = lane >> 4;

  for(int i = t; i < NQBIN; i += 256) shh[i] = 0;

  f32x4 acc[4][4];
  #pragma unroll
  for(int i = 0; i < 4; i++)
    #pragma unroll
    for(int j = 0; j < 4; j++) acc[i][j] = (f32x4){0.f, 0.f, 0.f, 0.f};

  // per-lane fragment bases
  const unsigned short* ahp = CmH + ((size_t)(hp0 + wm + fr) << 9) + fg * 8;
  const unsigned short* alp = CmL + ((size_t)(hp0 + wm + fr) << 9) + fg * 8;
  const unsigned short* bp  = t1h + (size_t)img * HW + ((size_t)(w0 + wn + fr) << 9) + fg * 8;

  for(int k0 = 0; k0 < 512; k0 += 32){
    bf16x8 ah[4], al[4], bv[4];
    #pragma unroll
    for(int i = 0; i < 4; i++){
      ah[i] = *(const bf16x8*)(ahp + i * 8192 + k0);
      al[i] = *(const bf16x8*)(alp + i * 8192 + k0);
    }
    #pragma unroll
    for(int j = 0; j < 4; j++)
      bv[j] = *(const bf16x8*)(bp + j * 8192 + k0);

    #pragma unroll
    for(int i = 0; i < 4; i++)
      #pragma unroll
      for(int j = 0; j < 4; j++){
        acc[i][j] = __builtin_amdgcn_mfma_f32_16x16x32_bf16(ah[i], bv[j], acc[i][j], 0, 0, 0);
        acc[i][j] = __builtin_amdgcn_mfma_f32_16x16x32_bf16(al[i], bv[j], acc[i][j], 0, 0, 0);
      }
  }
  __syncthreads();   // histogram zeros visible

  float* rimg = res + (size_t)img * HW;
  #pragma unroll
  for(int i = 0; i < 4; i++)
    #pragma unroll
    for(int j = 0; j < 4; j++){
      f32x4 a = acc[i][j];
      int w  = w0 + wn + j*16 + fr;
      int hp = hp0 + wm + i*16 + fg*4;
      #pragma unroll
      for(int r = 0; r < 4; r++){
        float v = fabsf(a[r]);
        rimg[((size_t)(hp + r) << 9) + w] = v;
        atomicAdd(&shh[min((int)(v * 256.f), NQBIN - 1)], 1u);
      }
    }
  __syncthreads();

  unsigned* hg = qh + (size_t)img * NQBIN;
  for(int i = t; i < NQBIN; i += 256){
    unsigned c = shh[i];
    if(c) atomicAdd(&hg[i], c);
  }
}

// ---- percentiles (linear interp at 3% / 97%) -> (lo, 1/(hi-lo)) ----
__global__ void k_pct(const unsigned* __restrict__ qh, float2* __restrict__ prm){
  int img = blockIdx.x, t = threadIdx.x;
  const unsigned* h = qh + (size_t)img * NQBIN;
  __shared__ unsigned sh[NQBIN];
  for(int i = t; i < NQBIN; i += 256) sh[i] = h[i];
  __syncthreads();
  if(t == 0){
    const unsigned targ[4] = {7864u, 7865u, 254278u, 254279u};
    float v[4]; unsigned cum = 0; int b = 0;
    for(int q = 0; q < 4; q++){
      while(cum + sh[b] <= targ[q]){ cum += sh[b]; ++b; }
      v[q] = (float)b * (1.0f / 256.0f);
    }
    double plo = 0.03 * 262143.0;
    double phi = 0.97 * 262143.0;
    float lo = v[0] + (float)(plo - 7864.0)   * (v[1] - v[0]);
    float hi = v[2] + (float)(phi - 254278.0) * (v[3] - v[2]);
    prm[img] = make_float2(lo, 1.0f / (hi - lo));
  }
}

// ---- in-place normalize: out = (res - lo) * inv * mask ----
__global__ __launch_bounds__(256) void k_norm(float* __restrict__ out, const float* __restrict__ mask,
                                              const float2* __restrict__ prm){
  size_t i4 = (size_t)blockIdx.x * blockDim.x + threadIdx.x;
  const size_t total4 = (size_t)NIMG * HW / 4;
  const size_t step = (size_t)gridDim.x * blockDim.x;
  for(; i4 < total4; i4 += step){
    size_t i = i4 * 4;
    int bc = (int)(i >> 18);
    int bb = bc / 3;
    size_t mi = ((size_t)bb << 18) + (i & 0x3FFFFu);
    float4 r = *(float4*)(out + i);
    float4 m = *(const float4*)(mask + mi);
    float2 p = prm[bc];
    float4 o;
    o.x = (r.x - p.x) * p.y * m.x;
    o.y = (r.y - p.x) * p.y * m.y;
    o.z = (r.z - p.x) * p.y * m.z;
    o.w = (r.w - p.x) * p.y * m.w;
    *(float4*)(out + i) = o;
  }
}

extern "C" void kernel_launch(void* const* d_in, const int* in_sizes, int n_in,
                              void* d_out, int out_size, void* d_ws, size_t ws_size,
                              hipStream_t stream)
{
  const float* x       = (const float*)d_in[0];
  const float* mask    = (const float*)d_in[1];
  const float* fmap_in = (const float*)d_in[2];
  float* out = (float*)d_out;

  const size_t T1_BYTES = (size_t)NIMG * HW * 2;   // 50,331,648 (bf16 t1T)
  char* ws = (char*)d_ws;
  unsigned short* t1h = (unsigned short*)ws;        // lives rowpass..colpass
  // radix histograms alias the (not-yet-written) t1 region:
  unsigned* h1 = (unsigned*)ws;                                        // 1.5 MB
  unsigned* h2 = (unsigned*)(ws + (size_t)NIMG * 4096 * 4);            // 1.5 MB
  char* tail = ws + T1_BYTES;
  float*          Dir = (float*)tail;                                  // 2048 B
  unsigned short* CmH = (unsigned short*)(tail + 2048);                // 512 KB
  unsigned short* CmL = (unsigned short*)(tail + 2048 + 524288);       // 512 KB
  char* tail2 = tail + 2048 + 1048576;
  float*  med  = (float*)tail2;                     // 512 B slot
  uint2*  sel1 = (uint2*)(tail2 + 512);             // 768 B
  float2* prm  = (float2*)(tail2 + 1536);           // 768 B
  unsigned* qh = (unsigned*)(tail2 + 2560);         // 96*4096*4 = 1.5 MB (NOT aliased with t1h)

  k_dir<<<512, 256, 0, stream>>>(fmap_in, Dir);
  k_cmat<<<512, 256, 0, stream>>>(Dir, CmH, CmL);

  // 2-pass LDS radix select: median prefix to 24 bits (midpoint, err <= 8e-6)
  hipMemsetAsync(h1, 0, (size_t)NIMG * 4096 * 4 * 2, stream);
  k_p1<<<NIMG * 8, 256, 0, stream>>>(x, h1);
  k_scan1<<<NIMG, 256, 0, stream>>>(h1, sel1);
  k_p2<<<NIMG * 8, 256, 0, stream>>>(x, sel1, h2);
  k_scan_med<<<NIMG, 256, 0, stream>>>(h2, sel1, med);

  hipMemsetAsync(qh, 0, (size_t)NIMG * NQBIN * 4, stream);
  k_rowpass<<<1536, 256, 0, stream>>>(x, mask, med, CmH, CmL, t1h);
  k_colpass<<<1536, 256, 0, stream>>>(t1h, CmH, CmL, out, qh);

  k_pct<<<NIMG, 256, 0, stream>>>(qh, prm);
  k_norm<<<2048, 256, 0, stream>>>(out, mask, prm);
}

// Round 8
// 329.265 us; speedup vs baseline: 1.5648x; 1.2806x over previous
//
#include <hip/hip_runtime.h>
#include <math.h>

#define HW 262144     // 512*512
#define NIMG 96       // B*C
#define NQBIN 4096

typedef __attribute__((ext_vector_type(8))) short bf16x8;
typedef __attribute__((ext_vector_type(4))) float f32x4;

// ---- helpers ----
__device__ __forceinline__ unsigned fmap_u(float f){
  unsigned u = __float_as_uint(f);
  return (u & 0x80000000u) ? ~u : (u | 0x80000000u);
}
__device__ __forceinline__ float funmap_u(unsigned u){
  unsigned v = (u & 0x80000000u) ? (u & 0x7fffffffu) : ~u;
  return __uint_as_float(v);
}
__device__ __forceinline__ unsigned bf16rne(float f){
  unsigned u = __float_as_uint(f);
  return (u + 0x7fffu + ((u >> 16) & 1u)) >> 16;
}
__device__ __forceinline__ void split2(float v, unsigned &h, unsigned &l){
  h = bf16rne(v);
  float fh = __uint_as_float(h << 16);
  l = bf16rne(v - fh);
}

// global -> LDS direct DMA, 16 B per lane. LDS dest = uniform base + lane*16.
typedef __attribute__((address_space(3))) unsigned lds_u;
typedef const __attribute__((address_space(1))) unsigned glb_u;
__device__ __forceinline__ void gll16(const void* g, void* l){
  __builtin_amdgcn_global_load_lds((glb_u*)g, (lds_u*)l, 16, 0, 0);
}

// ---- Dir[n] = Re( ifft(filter_map row 0) )[n], computed in double ----
__global__ void k_dir(const float* __restrict__ fmap_in, float* __restrict__ Dir){
  int n = blockIdx.x;
  int t = threadIdx.x;
  double s = 0.0;
  for(int c = t; c < 512; c += 256){
    int a = (c * n) & 511;
    s += (double)fmap_in[c] * cos(6.283185307179586476925287 * (double)a / 512.0);
  }
  __shared__ double red[256];
  red[t] = s; __syncthreads();
  for(int off = 128; off; off >>= 1){
    if(t < off) red[t] += red[t + off];
    __syncthreads();
  }
  if(t == 0) Dir[n] = (float)(red[0] / 512.0);
}

// ---- Cm[a][b] = Dir[(a-b)&511], split bf16 hi/lo (1 MB, L2-resident) ----
__global__ void k_cmat(const float* __restrict__ Dir, unsigned short* __restrict__ CmH,
                       unsigned short* __restrict__ CmL){
  int a = blockIdx.x;
  for(int b = threadIdx.x; b < 512; b += 256){
    float d = Dir[(a - b) & 511];
    unsigned h, l; split2(d, h, l);
    CmH[(size_t)a * 512 + b] = (unsigned short)h;
    CmL[(size_t)a * 512 + b] = (unsigned short)l;
  }
}

// ==== exact-to-24-bits median via 2-pass LDS radix select (12 / 12 bits) ====
__global__ __launch_bounds__(256) void k_p1(const float* __restrict__ x, unsigned* __restrict__ h){
  __shared__ unsigned sh[4096];
  const int img  = blockIdx.x >> 3;
  const int part = blockIdx.x & 7;
  const float4* p = (const float4*)(x + (size_t)img * HW + (size_t)part * 32768);
  for(int i = threadIdx.x; i < 4096; i += 256) sh[i] = 0;
  __syncthreads();
  for(int i = threadIdx.x; i < 8192; i += 256){
    float4 v = p[i];
    atomicAdd(&sh[fmap_u(v.x) >> 20], 1u);
    atomicAdd(&sh[fmap_u(v.y) >> 20], 1u);
    atomicAdd(&sh[fmap_u(v.z) >> 20], 1u);
    atomicAdd(&sh[fmap_u(v.w) >> 20], 1u);
  }
  __syncthreads();
  unsigned* hh = h + (size_t)img * 4096;
  for(int i = threadIdx.x; i < 4096; i += 256){
    unsigned c = sh[i];
    if(c) atomicAdd(&hh[i], c);
  }
}

__global__ __launch_bounds__(256) void k_p2(const float* __restrict__ x, const uint2* __restrict__ sel1,
                                            unsigned* __restrict__ h){
  __shared__ unsigned sh[4096];
  const int img  = blockIdx.x >> 3;
  const int part = blockIdx.x & 7;
  const unsigned b1 = sel1[img].x;
  const float4* p = (const float4*)(x + (size_t)img * HW + (size_t)part * 32768);
  for(int i = threadIdx.x; i < 4096; i += 256) sh[i] = 0;
  __syncthreads();
  for(int i = threadIdx.x; i < 8192; i += 256){
    float4 v = p[i];
    unsigned u;
    u = fmap_u(v.x); if((u >> 20) == b1) atomicAdd(&sh[(u >> 8) & 0xFFFu], 1u);
    u = fmap_u(v.y); if((u >> 20) == b1) atomicAdd(&sh[(u >> 8) & 0xFFFu], 1u);
    u = fmap_u(v.z); if((u >> 20) == b1) atomicAdd(&sh[(u >> 8) & 0xFFFu], 1u);
    u = fmap_u(v.w); if((u >> 20) == b1) atomicAdd(&sh[(u >> 8) & 0xFFFu], 1u);
  }
  __syncthreads();
  unsigned* hh = h + (size_t)img * 4096;
  for(int i = threadIdx.x; i < 4096; i += 256){
    unsigned c = sh[i];
    if(c) atomicAdd(&hh[i], c);
  }
}

__global__ void k_scan1(const unsigned* __restrict__ h, uint2* __restrict__ osel){
  int img = blockIdx.x, t = threadIdx.x;
  const unsigned* hh = h + (size_t)img * 4096;
  __shared__ unsigned csum[256];
  unsigned s = 0;
  for(int j = 0; j < 16; j++) s += hh[t * 16 + j];
  csum[t] = s; __syncthreads();
  if(t == 0){
    unsigned k = 131071u, cum = 0; int chunk = 0;
    for(; chunk < 256; ++chunk){ if(cum + csum[chunk] > k) break; cum += csum[chunk]; }
    int b = chunk * 16;
    for(;; ++b){ unsigned c = hh[b]; if(cum + c > k) break; cum += c; }
    osel[img] = make_uint2((unsigned)b, k - cum);
  }
}

__global__ void k_scan_med(const unsigned* __restrict__ h, const uint2* __restrict__ sel1,
                           float* __restrict__ med){
  int img = blockIdx.x, t = threadIdx.x;
  const unsigned* hh = h + (size_t)img * 4096;
  __shared__ unsigned csum[256];
  unsigned s = 0;
  for(int j = 0; j < 16; j++) s += hh[t * 16 + j];
  csum[t] = s; __syncthreads();
  if(t == 0){
    unsigned k = sel1[img].y, cum = 0; int chunk = 0;
    for(; chunk < 256; ++chunk){ if(cum + csum[chunk] > k) break; cum += csum[chunk]; }
    int b = chunk * 16;
    for(;; ++b){ unsigned c = hh[b]; if(cum + c > k) break; cum += c; }
    unsigned u = (sel1[img].x << 20) | ((unsigned)b << 8) | 128u;
    med[img] = funmap_u(u) + 0.2f;
  }
}

// ==== MFMA row pass, BK=64, linear LDS + blk^(row&7) swizzle ====
// A (x: pad+convert) reg-staged; B (CmH/CmL) via global_load_lds w/ pre-swizzled source.
// t1T[img][n][h] = bf16( sum_k padded[r][k] * Cm[n][k] )
__global__ __launch_bounds__(256, 2) void k_rowpass(
    const float* __restrict__ x, const float* __restrict__ mask,
    const float* __restrict__ med,
    const unsigned short* __restrict__ CmH, const unsigned short* __restrict__ CmL,
    unsigned short* __restrict__ t1h)
{
  __shared__ __align__(16) unsigned short As [128 * 64];   // 16 KB
  __shared__ __align__(16) unsigned short BsH[128 * 64];   // 16 KB
  __shared__ __align__(16) unsigned short BsL[128 * 64];   // 16 KB

  // XCD swizzle: 4 sibling n-blocks (same rows) on the same XCD
  const int b    = blockIdx.x;           // 0..1535
  const int xcd  = b & 7;
  const int i8   = b >> 3;               // 0..191
  const int rblk = xcd * 48 + (i8 >> 2); // 0..383
  const int nblk = i8 & 3;
  const int r0 = rblk * 128;
  const int n0 = nblk * 128;
  const int bc = r0 >> 9;
  const int bb = bc / 3;
  const float mv = med[bc];

  const int t    = threadIdx.x;
  const int lane = t & 63;
  const int wv   = t >> 6;
  const int wm   = (wv >> 1) * 64;
  const int wn   = (wv & 1) * 64;
  const int fr   = lane & 15;
  const int fg   = lane >> 4;
  const int sw   = lane & 7;             // = row&7 for all fragment rows

  f32x4 acc[4][4];
  #pragma unroll
  for(int i = 0; i < 4; i++)
    #pragma unroll
    for(int j = 0; j < 4; j++) acc[i][j] = (f32x4){0.f, 0.f, 0.f, 0.f};

  // A staging: thread t -> row t>>1, k-half p=t&1 (32 ushorts)
  const int srow = t >> 1;
  const int p    = t & 1;
  const float* xr = x    + ((size_t)(r0 + srow) << 9) + p * 32;
  const float* mr = mask + (size_t)bb * HW + ((size_t)((r0 + srow) & 511) << 9) + p * 32;

  // B DMA: wave wv covers rows [wv*32, wv*32+32), 8 rows per instruction.
  // lane l -> row +(l>>3), source block (l&7)^(l>>3)  (pre-swizzled source)
  const int brow = wv * 32 + (lane >> 3);
  const int lblk = (lane & 7) ^ (lane >> 3);
  const unsigned short* bhsrc = CmH + ((size_t)(n0 + brow) << 9) + lblk * 8;
  const unsigned short* blsrc = CmL + ((size_t)(n0 + brow) << 9) + lblk * 8;

  for(int it = 0; it < 8; ++it){
    const int k0 = it * 64;
    __syncthreads();   // previous compute done; LDS safe to overwrite

    // --- B staging: 8x global_load_lds (pure DMA, no VGPR round-trip) ---
    #pragma unroll
    for(int i = 0; i < 4; i++){
      gll16(bhsrc + (((size_t)i * 8) << 9) + k0, &BsH[(wv * 32 + i * 8) * 64]);
      gll16(blsrc + (((size_t)i * 8) << 9) + k0, &BsL[(wv * 32 + i * 8) * 64]);
    }

    // --- A staging: load, mask-select, bf16 convert, swizzled LDS write ---
    {
      unsigned hp[16];
      #pragma unroll
      for(int q = 0; q < 8; q++){
        float4 xv = *(const float4*)(xr + k0 + q * 4);
        float4 mk = *(const float4*)(mr + k0 + q * 4);
        unsigned h0 = bf16rne((mk.x != 0.f) ? xv.x : mv);
        unsigned h1 = bf16rne((mk.y != 0.f) ? xv.y : mv);
        unsigned h2 = bf16rne((mk.z != 0.f) ? xv.z : mv);
        unsigned h3 = bf16rne((mk.w != 0.f) ? xv.w : mv);
        hp[q*2]   = (h1 << 16) | h0;
        hp[q*2+1] = (h3 << 16) | h2;
      }
      #pragma unroll
      for(int w = 0; w < 4; w++){
        int blk = (p * 4 + w) ^ (srow & 7);
        *(uint4*)&As[srow * 64 + blk * 8] =
            make_uint4(hp[w*4], hp[w*4+1], hp[w*4+2], hp[w*4+3]);
      }
    }
    __syncthreads();   // drains vmcnt (DMA) + lgkm (A writes)

    // --- compute: swizzled conflict-free b128 reads + 64 MFMAs ---
    bf16x8 ah[4][2], bh[4][2], bl[4][2];
    #pragma unroll
    for(int i = 0; i < 4; i++)
      #pragma unroll
      for(int ks = 0; ks < 2; ks++)
        ah[i][ks] = *(const bf16x8*)&As[(wm + i*16 + fr) * 64 + (((ks*4 + fg) ^ sw) << 3)];
    #pragma unroll
    for(int j = 0; j < 4; j++)
      #pragma unroll
      for(int ks = 0; ks < 2; ks++){
        bh[j][ks] = *(const bf16x8*)&BsH[(wn + j*16 + fr) * 64 + (((ks*4 + fg) ^ sw) << 3)];
        bl[j][ks] = *(const bf16x8*)&BsL[(wn + j*16 + fr) * 64 + (((ks*4 + fg) ^ sw) << 3)];
      }
    #pragma unroll
    for(int i = 0; i < 4; i++)
      #pragma unroll
      for(int j = 0; j < 4; j++){
        acc[i][j] = __builtin_amdgcn_mfma_f32_16x16x32_bf16(ah[i][0], bh[j][0], acc[i][j], 0, 0, 0);
        acc[i][j] = __builtin_amdgcn_mfma_f32_16x16x32_bf16(ah[i][0], bl[j][0], acc[i][j], 0, 0, 0);
        acc[i][j] = __builtin_amdgcn_mfma_f32_16x16x32_bf16(ah[i][1], bh[j][1], acc[i][j], 0, 0, 0);
        acc[i][j] = __builtin_amdgcn_mfma_f32_16x16x32_bf16(ah[i][1], bl[j][1], acc[i][j], 0, 0, 0);
      }
  }

  // --- store t1 transposed as single bf16: t1T[img][n][h] ---
  const int img = r0 >> 9;
  const int hb  = r0 & 511;
  #pragma unroll
  for(int i = 0; i < 4; i++)
    #pragma unroll
    for(int j = 0; j < 4; j++){
      f32x4 a = acc[i][j];
      unsigned b0 = bf16rne(a[0]), b1 = bf16rne(a[1]), b2 = bf16rne(a[2]), b3 = bf16rne(a[3]);
      int n = n0 + wn + j*16 + fr;
      int h = hb + wm + i*16 + fg*4;
      *(uint2*)&t1h[(size_t)img * HW + ((size_t)n << 9) + h] =
          make_uint2((b1<<16)|b0, (b3<<16)|b2);
    }
}

// ==== MFMA col pass, BK=64, all operands via global_load_lds; fused q-histogram ====
// res[img][h'][w] = | sum_h Cm[h'][h] * t1T[img][w][h] |
__global__ __launch_bounds__(256, 2) void k_colpass(
    const unsigned short* __restrict__ t1h,
    const unsigned short* __restrict__ CmH, const unsigned short* __restrict__ CmL,
    float* __restrict__ res, unsigned* __restrict__ qh)
{
  __shared__ __align__(16) unsigned short SH[3 * 128 * 64];   // 48 KB
  unsigned short* AsH = SH;
  unsigned short* AsL = SH + 8192;
  unsigned short* Bs  = SH + 16384;

  // XCD swizzle: all 16 blocks of one image on the same XCD (t1 image L2-resident)
  const int b    = blockIdx.x;           // 0..1535
  const int xcd  = b & 7;
  const int i8   = b >> 3;               // 0..191
  const int img  = xcd * 12 + (i8 >> 4);
  const int r16  = i8 & 15;
  const int hp0  = (r16 >> 2) * 128;
  const int w0   = (r16 & 3) * 128;

  const int t    = threadIdx.x;
  const int lane = t & 63;
  const int wv   = t >> 6;
  const int wm   = (wv >> 1) * 64;
  const int wn   = (wv & 1) * 64;
  const int fr   = lane & 15;
  const int fg   = lane >> 4;
  const int sw   = lane & 7;

  f32x4 acc[4][4];
  #pragma unroll
  for(int i = 0; i < 4; i++)
    #pragma unroll
    for(int j = 0; j < 4; j++) acc[i][j] = (f32x4){0.f, 0.f, 0.f, 0.f};

  const int brow = wv * 32 + (lane >> 3);
  const int lblk = (lane & 7) ^ (lane >> 3);
  const unsigned short* ahsrc = CmH + ((size_t)(hp0 + brow) << 9) + lblk * 8;
  const unsigned short* alsrc = CmL + ((size_t)(hp0 + brow) << 9) + lblk * 8;
  const unsigned short* bsrc  = t1h + (size_t)img * HW + ((size_t)(w0 + brow) << 9) + lblk * 8;

  for(int it = 0; it < 8; ++it){
    const int k0 = it * 64;
    __syncthreads();

    #pragma unroll
    for(int i = 0; i < 4; i++){
      gll16(ahsrc + (((size_t)i * 8) << 9) + k0, &AsH[(wv * 32 + i * 8) * 64]);
      gll16(alsrc + (((size_t)i * 8) << 9) + k0, &AsL[(wv * 32 + i * 8) * 64]);
      gll16(bsrc  + (((size_t)i * 8) << 9) + k0, &Bs [(wv * 32 + i * 8) * 64]);
    }
    __syncthreads();   // drain DMA

    bf16x8 ah[4][2], al[4][2], bv[4][2];
    #pragma unroll
    for(int i = 0; i < 4; i++)
      #pragma unroll
      for(int ks = 0; ks < 2; ks++){
        ah[i][ks] = *(const bf16x8*)&AsH[(wm + i*16 + fr) * 64 + (((ks*4 + fg) ^ sw) << 3)];
        al[i][ks] = *(const bf16x8*)&AsL[(wm + i*16 + fr) * 64 + (((ks*4 + fg) ^ sw) << 3)];
      }
    #pragma unroll
    for(int j = 0; j < 4; j++)
      #pragma unroll
      for(int ks = 0; ks < 2; ks++)
        bv[j][ks] = *(const bf16x8*)&Bs[(wn + j*16 + fr) * 64 + (((ks*4 + fg) ^ sw) << 3)];

    #pragma unroll
    for(int i = 0; i < 4; i++)
      #pragma unroll
      for(int j = 0; j < 4; j++){
        acc[i][j] = __builtin_amdgcn_mfma_f32_16x16x32_bf16(ah[i][0], bv[j][0], acc[i][j], 0, 0, 0);
        acc[i][j] = __builtin_amdgcn_mfma_f32_16x16x32_bf16(al[i][0], bv[j][0], acc[i][j], 0, 0, 0);
        acc[i][j] = __builtin_amdgcn_mfma_f32_16x16x32_bf16(ah[i][1], bv[j][1], acc[i][j], 0, 0, 0);
        acc[i][j] = __builtin_amdgcn_mfma_f32_16x16x32_bf16(al[i][1], bv[j][1], acc[i][j], 0, 0, 0);
      }
  }
  __syncthreads();   // all waves done reading SH before histogram reuse

  // --- epilogue: store |acc| and histogram it in LDS (reuse tile buffer) ---
  unsigned* shh = (unsigned*)SH;          // 4096 bins = 16 KB <= 48 KB
  for(int i = t; i < NQBIN; i += 256) shh[i] = 0;
  __syncthreads();

  float* rimg = res + (size_t)img * HW;
  #pragma unroll
  for(int i = 0; i < 4; i++)
    #pragma unroll
    for(int j = 0; j < 4; j++){
      f32x4 a = acc[i][j];
      int w  = w0 + wn + j*16 + fr;
      int hp = hp0 + wm + i*16 + fg*4;
      #pragma unroll
      for(int r = 0; r < 4; r++){
        float v = fabsf(a[r]);
        rimg[((size_t)(hp + r) << 9) + w] = v;
        atomicAdd(&shh[min((int)(v * 256.f), NQBIN - 1)], 1u);
      }
    }
  __syncthreads();

  unsigned* hg = qh + (size_t)img * NQBIN;
  for(int i = t; i < NQBIN; i += 256){
    unsigned c = shh[i];
    if(c) atomicAdd(&hg[i], c);
  }
}

// ---- percentiles (linear interp at 3% / 97%) -> (lo, 1/(hi-lo)) ----
__global__ void k_pct(const unsigned* __restrict__ qh, float2* __restrict__ prm){
  int img = blockIdx.x, t = threadIdx.x;
  const unsigned* h = qh + (size_t)img * NQBIN;
  __shared__ unsigned sh[NQBIN];
  for(int i = t; i < NQBIN; i += 256) sh[i] = h[i];
  __syncthreads();
  if(t == 0){
    const unsigned targ[4] = {7864u, 7865u, 254278u, 254279u};
    float v[4]; unsigned cum = 0; int b = 0;
    for(int q = 0; q < 4; q++){
      while(cum + sh[b] <= targ[q]){ cum += sh[b]; ++b; }
      v[q] = (float)b * (1.0f / 256.0f);
    }
    double plo = 0.03 * 262143.0;
    double phi = 0.97 * 262143.0;
    float lo = v[0] + (float)(plo - 7864.0)   * (v[1] - v[0]);
    float hi = v[2] + (float)(phi - 254278.0) * (v[3] - v[2]);
    prm[img] = make_float2(lo, 1.0f / (hi - lo));
  }
}

// ---- in-place normalize: out = (res - lo) * inv * mask ----
__global__ __launch_bounds__(256) void k_norm(float* __restrict__ out, const float* __restrict__ mask,
                                              const float2* __restrict__ prm){
  size_t i4 = (size_t)blockIdx.x * blockDim.x + threadIdx.x;
  const size_t total4 = (size_t)NIMG * HW / 4;
  const size_t step = (size_t)gridDim.x * blockDim.x;
  for(; i4 < total4; i4 += step){
    size_t i = i4 * 4;
    int bc = (int)(i >> 18);
    int bb = bc / 3;
    size_t mi = ((size_t)bb << 18) + (i & 0x3FFFFu);
    float4 r = *(float4*)(out + i);
    float4 m = *(const float4*)(mask + mi);
    float2 p = prm[bc];
    float4 o;
    o.x = (r.x - p.x) * p.y * m.x;
    o.y = (r.y - p.x) * p.y * m.y;
    o.z = (r.z - p.x) * p.y * m.z;
    o.w = (r.w - p.x) * p.y * m.w;
    *(float4*)(out + i) = o;
  }
}

extern "C" void kernel_launch(void* const* d_in, const int* in_sizes, int n_in,
                              void* d_out, int out_size, void* d_ws, size_t ws_size,
                              hipStream_t stream)
{
  const float* x       = (const float*)d_in[0];
  const float* mask    = (const float*)d_in[1];
  const float* fmap_in = (const float*)d_in[2];
  float* out = (float*)d_out;

  const size_t T1_BYTES = (size_t)NIMG * HW * 2;   // 50,331,648 (bf16 t1T)
  char* ws = (char*)d_ws;
  unsigned short* t1h = (unsigned short*)ws;        // lives rowpass..colpass
  // radix histograms alias the (not-yet-written) t1 region:
  unsigned* h1 = (unsigned*)ws;                                        // 1.5 MB
  unsigned* h2 = (unsigned*)(ws + (size_t)NIMG * 4096 * 4);            // 1.5 MB
  char* tail = ws + T1_BYTES;
  float*          Dir = (float*)tail;                                  // 2048 B
  unsigned short* CmH = (unsigned short*)(tail + 2048);                // 512 KB
  unsigned short* CmL = (unsigned short*)(tail + 2048 + 524288);       // 512 KB
  char* tail2 = tail + 2048 + 1048576;
  float*  med  = (float*)tail2;                     // 512 B slot
  uint2*  sel1 = (uint2*)(tail2 + 512);             // 768 B
  float2* prm  = (float2*)(tail2 + 1536);           // 768 B
  unsigned* qh = (unsigned*)(tail2 + 2560);         // 96*4096*4 = 1.5 MB (NOT aliased with t1h)

  k_dir<<<512, 256, 0, stream>>>(fmap_in, Dir);
  k_cmat<<<512, 256, 0, stream>>>(Dir, CmH, CmL);

  // 2-pass LDS radix select: median prefix to 24 bits (midpoint, err <= 8e-6)
  hipMemsetAsync(h1, 0, (size_t)NIMG * 4096 * 4 * 2, stream);
  k_p1<<<NIMG * 8, 256, 0, stream>>>(x, h1);
  k_scan1<<<NIMG, 256, 0, stream>>>(h1, sel1);
  k_p2<<<NIMG * 8, 256, 0, stream>>>(x, sel1, h2);
  k_scan_med<<<NIMG, 256, 0, stream>>>(h2, sel1, med);

  hipMemsetAsync(qh, 0, (size_t)NIMG * NQBIN * 4, stream);
  k_rowpass<<<1536, 256, 0, stream>>>(x, mask, med, CmH, CmL, t1h);
  k_colpass<<<1536, 256, 0, stream>>>(t1h, CmH, CmL, out, qh);

  k_pct<<<NIMG, 256, 0, stream>>>(qh, prm);
  k_norm<<<2048, 256, 0, stream>>>(out, mask, prm);
}

// Round 9
// 316.670 us; speedup vs baseline: 1.6271x; 1.0398x over previous
//
#include <hip/hip_runtime.h>
#include <math.h>

#define HW 262144     // 512*512
#define NIMG 96       // B*C
#define NQBIN 4096

typedef __attribute__((ext_vector_type(8))) short bf16x8;
typedef __attribute__((ext_vector_type(4))) float f32x4;

// ---- helpers ----
__device__ __forceinline__ unsigned fmap_u(float f){
  unsigned u = __float_as_uint(f);
  return (u & 0x80000000u) ? ~u : (u | 0x80000000u);
}
__device__ __forceinline__ float funmap_u(unsigned u){
  unsigned v = (u & 0x80000000u) ? (u & 0x7fffffffu) : ~u;
  return __uint_as_float(v);
}
__device__ __forceinline__ unsigned bf16rne(float f){
  unsigned u = __float_as_uint(f);
  return (u + 0x7fffu + ((u >> 16) & 1u)) >> 16;
}
__device__ __forceinline__ void split2(float v, unsigned &h, unsigned &l){
  h = bf16rne(v);
  float fh = __uint_as_float(h << 16);
  l = bf16rne(v - fh);
}

// global -> LDS direct DMA, 16 B per lane. LDS dest = wave-uniform base + lane*16.
typedef __attribute__((address_space(3))) unsigned lds_u;
typedef const __attribute__((address_space(1))) unsigned glb_u;
__device__ __forceinline__ void gll16(const void* g, void* l){
  __builtin_amdgcn_global_load_lds((glb_u*)g, (lds_u*)l, 16, 0, 0);
}

// ---- Dir[n] = Re( ifft(filter_map row 0) )[n], computed in double ----
__global__ void k_dir(const float* __restrict__ fmap_in, float* __restrict__ Dir){
  int n = blockIdx.x;
  int t = threadIdx.x;
  double s = 0.0;
  for(int c = t; c < 512; c += 256){
    int a = (c * n) & 511;
    s += (double)fmap_in[c] * cos(6.283185307179586476925287 * (double)a / 512.0);
  }
  __shared__ double red[256];
  red[t] = s; __syncthreads();
  for(int off = 128; off; off >>= 1){
    if(t < off) red[t] += red[t + off];
    __syncthreads();
  }
  if(t == 0) Dir[n] = (float)(red[0] / 512.0);
}

// ---- Cm[a][b] = Dir[(a-b)&511], split bf16 hi/lo (1 MB, L2-resident) ----
__global__ void k_cmat(const float* __restrict__ Dir, unsigned short* __restrict__ CmH,
                       unsigned short* __restrict__ CmL){
  int a = blockIdx.x;
  for(int b = threadIdx.x; b < 512; b += 256){
    float d = Dir[(a - b) & 511];
    unsigned h, l; split2(d, h, l);
    CmH[(size_t)a * 512 + b] = (unsigned short)h;
    CmL[(size_t)a * 512 + b] = (unsigned short)l;
  }
}

// ==== exact-to-24-bits median via 2-pass LDS radix select (12 / 12 bits) ====
__global__ __launch_bounds__(256) void k_p1(const float* __restrict__ x, unsigned* __restrict__ h){
  __shared__ unsigned sh[4096];
  const int img  = blockIdx.x >> 3;
  const int part = blockIdx.x & 7;
  const float4* p = (const float4*)(x + (size_t)img * HW + (size_t)part * 32768);
  for(int i = threadIdx.x; i < 4096; i += 256) sh[i] = 0;
  __syncthreads();
  for(int i = threadIdx.x; i < 8192; i += 256){
    float4 v = p[i];
    atomicAdd(&sh[fmap_u(v.x) >> 20], 1u);
    atomicAdd(&sh[fmap_u(v.y) >> 20], 1u);
    atomicAdd(&sh[fmap_u(v.z) >> 20], 1u);
    atomicAdd(&sh[fmap_u(v.w) >> 20], 1u);
  }
  __syncthreads();
  unsigned* hh = h + (size_t)img * 4096;
  for(int i = threadIdx.x; i < 4096; i += 256){
    unsigned c = sh[i];
    if(c) atomicAdd(&hh[i], c);
  }
}

__global__ __launch_bounds__(256) void k_p2(const float* __restrict__ x, const uint2* __restrict__ sel1,
                                            unsigned* __restrict__ h){
  __shared__ unsigned sh[4096];
  const int img  = blockIdx.x >> 3;
  const int part = blockIdx.x & 7;
  const unsigned b1 = sel1[img].x;
  const float4* p = (const float4*)(x + (size_t)img * HW + (size_t)part * 32768);
  for(int i = threadIdx.x; i < 4096; i += 256) sh[i] = 0;
  __syncthreads();
  for(int i = threadIdx.x; i < 8192; i += 256){
    float4 v = p[i];
    unsigned u;
    u = fmap_u(v.x); if((u >> 20) == b1) atomicAdd(&sh[(u >> 8) & 0xFFFu], 1u);
    u = fmap_u(v.y); if((u >> 20) == b1) atomicAdd(&sh[(u >> 8) & 0xFFFu], 1u);
    u = fmap_u(v.z); if((u >> 20) == b1) atomicAdd(&sh[(u >> 8) & 0xFFFu], 1u);
    u = fmap_u(v.w); if((u >> 20) == b1) atomicAdd(&sh[(u >> 8) & 0xFFFu], 1u);
  }
  __syncthreads();
  unsigned* hh = h + (size_t)img * 4096;
  for(int i = threadIdx.x; i < 4096; i += 256){
    unsigned c = sh[i];
    if(c) atomicAdd(&hh[i], c);
  }
}

__global__ void k_scan1(const unsigned* __restrict__ h, uint2* __restrict__ osel){
  int img = blockIdx.x, t = threadIdx.x;
  const unsigned* hh = h + (size_t)img * 4096;
  __shared__ unsigned csum[256];
  unsigned s = 0;
  for(int j = 0; j < 16; j++) s += hh[t * 16 + j];
  csum[t] = s; __syncthreads();
  if(t == 0){
    unsigned k = 131071u, cum = 0; int chunk = 0;
    for(; chunk < 256; ++chunk){ if(cum + csum[chunk] > k) break; cum += csum[chunk]; }
    int b = chunk * 16;
    for(;; ++b){ unsigned c = hh[b]; if(cum + c > k) break; cum += c; }
    osel[img] = make_uint2((unsigned)b, k - cum);
  }
}

__global__ void k_scan_med(const unsigned* __restrict__ h, const uint2* __restrict__ sel1,
                           float* __restrict__ med){
  int img = blockIdx.x, t = threadIdx.x;
  const unsigned* hh = h + (size_t)img * 4096;
  __shared__ unsigned csum[256];
  unsigned s = 0;
  for(int j = 0; j < 16; j++) s += hh[t * 16 + j];
  csum[t] = s; __syncthreads();
  if(t == 0){
    unsigned k = sel1[img].y, cum = 0; int chunk = 0;
    for(; chunk < 256; ++chunk){ if(cum + csum[chunk] > k) break; cum += csum[chunk]; }
    int b = chunk * 16;
    for(;; ++b){ unsigned c = hh[b]; if(cum + c > k) break; cum += c; }
    unsigned u = (sel1[img].x << 20) | ((unsigned)b << 8) | 128u;
    med[img] = funmap_u(u) + 0.2f;
  }
}

// ---- prepad: xh[img][h][k] = bf16( mask ? x : med[img] )  (hoists conversion out of GEMM) ----
__global__ __launch_bounds__(256) void k_prepad(
    const float* __restrict__ x, const float* __restrict__ mask,
    const float* __restrict__ med, unsigned short* __restrict__ xh)
{
  size_t u8 = (size_t)blockIdx.x * 256 + threadIdx.x;   // unit = 8 elements
  size_t i  = u8 * 8;
  int img = (int)(i >> 18);
  size_t mi = ((size_t)(img / 3) << 18) + (i & 0x3FFFFu);
  const float mv = med[img];
  unsigned hp[4];
  #pragma unroll
  for(int q = 0; q < 2; q++){
    float4 xv = *(const float4*)(x + i + q * 4);
    float4 mk = *(const float4*)(mask + mi + q * 4);
    unsigned h0 = bf16rne((mk.x != 0.f) ? xv.x : mv);
    unsigned h1 = bf16rne((mk.y != 0.f) ? xv.y : mv);
    unsigned h2 = bf16rne((mk.z != 0.f) ? xv.z : mv);
    unsigned h3 = bf16rne((mk.w != 0.f) ? xv.w : mv);
    hp[q*2]   = (h1 << 16) | h0;
    hp[q*2+1] = (h3 << 16) | h2;
  }
  *(uint4*)(xh + i) = make_uint4(hp[0], hp[1], hp[2], hp[3]);
}

// ==== MFMA row pass: 512 thr / 8 waves, BK=64, dbuf LDS, issue-early counted-vmcnt ====
// t1T[img][n][h] = bf16( sum_k xh[r][k] * Cm[n][k] )
__global__ __launch_bounds__(512, 1) void k_rowpass(
    const unsigned short* __restrict__ xh,
    const unsigned short* __restrict__ CmH, const unsigned short* __restrict__ CmL,
    unsigned short* __restrict__ t1h)
{
  __shared__ __align__(16) unsigned short As [2][8192];
  __shared__ __align__(16) unsigned short BsH[2][8192];
  __shared__ __align__(16) unsigned short BsL[2][8192];

  // XCD swizzle: 4 sibling n-blocks (same xh rows) on the same XCD
  const int b    = blockIdx.x;           // 0..1535
  const int xcd  = b & 7;
  const int i8   = b >> 3;               // 0..191
  const int rblk = xcd * 48 + (i8 >> 2); // 0..383
  const int nblk = i8 & 3;
  const int r0 = rblk * 128;
  const int n0 = nblk * 128;

  const int t    = threadIdx.x;
  const int lane = t & 63;
  const int wv   = t >> 6;               // 0..7
  const int wm   = (wv >> 2) * 64;       // 0,64   (row half)
  const int wn   = (wv & 3) * 32;        // 0..96  (col quarter)
  const int fr   = lane & 15;
  const int fg   = lane >> 4;
  const int sw   = lane & 7;

  // staging: wave wv + instr q cover rows [q*64 + wv*8, +8); lane l -> row +(l>>3), src block (l&7)^(l>>3)
  const int srow = lane >> 3;
  const int sblk = (lane & 7) ^ srow;
  const unsigned short* asrc  = xh  + ((size_t)(r0 + wv*8 + srow) << 9) + sblk * 8;
  const unsigned short* bhsrc = CmH + ((size_t)(n0 + wv*8 + srow) << 9) + sblk * 8;
  const unsigned short* blsrc = CmL + ((size_t)(n0 + wv*8 + srow) << 9) + sblk * 8;
  const int dbase = wv * 8 * 64;

  f32x4 acc[4][2];
  #pragma unroll
  for(int i = 0; i < 4; i++)
    #pragma unroll
    for(int j = 0; j < 2; j++) acc[i][j] = (f32x4){0.f, 0.f, 0.f, 0.f};

  auto STAGE = [&](int buf, int k0){
    #pragma unroll
    for(int q = 0; q < 2; q++){
      const size_t so = ((size_t)(q * 64) << 9) + k0;
      const int    dq = dbase + q * 64 * 64;
      gll16(asrc  + so, &As [buf][dq]);
      gll16(bhsrc + so, &BsH[buf][dq]);
      gll16(blsrc + so, &BsL[buf][dq]);
    }
  };
  auto COMPUTE = [&](int buf){
    bf16x8 af[4][2], bh[2][2], bl[2][2];
    #pragma unroll
    for(int i = 0; i < 4; i++)
      #pragma unroll
      for(int kq = 0; kq < 2; kq++){
        int row = wm + i*16 + fr;
        af[i][kq] = *(const bf16x8*)&As[buf][row*64 + (((kq*4 + fg) ^ sw) << 3)];
      }
    #pragma unroll
    for(int j = 0; j < 2; j++)
      #pragma unroll
      for(int kq = 0; kq < 2; kq++){
        int row = wn + j*16 + fr;
        bh[j][kq] = *(const bf16x8*)&BsH[buf][row*64 + (((kq*4 + fg) ^ sw) << 3)];
        bl[j][kq] = *(const bf16x8*)&BsL[buf][row*64 + (((kq*4 + fg) ^ sw) << 3)];
      }
    __builtin_amdgcn_s_setprio(1);
    #pragma unroll
    for(int i = 0; i < 4; i++)
      #pragma unroll
      for(int j = 0; j < 2; j++){
        acc[i][j] = __builtin_amdgcn_mfma_f32_16x16x32_bf16(af[i][0], bh[j][0], acc[i][j], 0, 0, 0);
        acc[i][j] = __builtin_amdgcn_mfma_f32_16x16x32_bf16(af[i][0], bl[j][0], acc[i][j], 0, 0, 0);
        acc[i][j] = __builtin_amdgcn_mfma_f32_16x16x32_bf16(af[i][1], bh[j][1], acc[i][j], 0, 0, 0);
        acc[i][j] = __builtin_amdgcn_mfma_f32_16x16x32_bf16(af[i][1], bl[j][1], acc[i][j], 0, 0, 0);
      }
    __builtin_amdgcn_s_setprio(0);
  };

  // prologue
  STAGE(0, 0);
  asm volatile("s_waitcnt vmcnt(0)" ::: "memory");
  __builtin_amdgcn_s_barrier();
  // main: issue next-tile DMA first, wait only for prev tile (vmcnt(6)), compute, barrier
  #pragma unroll
  for(int it = 0; it < 7; ++it){
    STAGE((it + 1) & 1, (it + 1) * 64);
    asm volatile("s_waitcnt vmcnt(6)" ::: "memory");
    __builtin_amdgcn_s_barrier();
    COMPUTE(it & 1);
    asm volatile("" ::: "memory");
    __builtin_amdgcn_s_barrier();
  }
  asm volatile("s_waitcnt vmcnt(0)" ::: "memory");
  __builtin_amdgcn_s_barrier();
  COMPUTE(1);

  // epilogue: t1 transposed single bf16
  const int img = r0 >> 9;
  const int hb  = r0 & 511;
  #pragma unroll
  for(int i = 0; i < 4; i++)
    #pragma unroll
    for(int j = 0; j < 2; j++){
      f32x4 a = acc[i][j];
      unsigned b0 = bf16rne(a[0]), b1 = bf16rne(a[1]), b2 = bf16rne(a[2]), b3 = bf16rne(a[3]);
      int n = n0 + wn + j*16 + fr;
      int h = hb + wm + i*16 + fg*4;
      *(uint2*)&t1h[(size_t)img * HW + ((size_t)n << 9) + h] =
          make_uint2((b1<<16)|b0, (b3<<16)|b2);
    }
}

// ==== MFMA col pass: same pipeline; A=Cm split, B=t1h; fused q-histogram ====
__global__ __launch_bounds__(512, 1) void k_colpass(
    const unsigned short* __restrict__ t1h,
    const unsigned short* __restrict__ CmH, const unsigned short* __restrict__ CmL,
    float* __restrict__ res, unsigned* __restrict__ qh)
{
  __shared__ __align__(16) unsigned short AsH[2][8192];
  __shared__ __align__(16) unsigned short AsL[2][8192];
  __shared__ __align__(16) unsigned short Bs [2][8192];

  // XCD swizzle: all 16 blocks of one image on the same XCD (t1 image L2-resident)
  const int b    = blockIdx.x;           // 0..1535
  const int xcd  = b & 7;
  const int i8   = b >> 3;               // 0..191
  const int img  = xcd * 12 + (i8 >> 4);
  const int r16  = i8 & 15;
  const int hp0  = (r16 >> 2) * 128;
  const int w0   = (r16 & 3) * 128;

  const int t    = threadIdx.x;
  const int lane = t & 63;
  const int wv   = t >> 6;
  const int wm   = (wv >> 2) * 64;
  const int wn   = (wv & 3) * 32;
  const int fr   = lane & 15;
  const int fg   = lane >> 4;
  const int sw   = lane & 7;

  const int srow = lane >> 3;
  const int sblk = (lane & 7) ^ srow;
  const unsigned short* ahsrc = CmH + ((size_t)(hp0 + wv*8 + srow) << 9) + sblk * 8;
  const unsigned short* alsrc = CmL + ((size_t)(hp0 + wv*8 + srow) << 9) + sblk * 8;
  const unsigned short* bsrc  = t1h + (size_t)img * HW + ((size_t)(w0 + wv*8 + srow) << 9) + sblk * 8;
  const int dbase = wv * 8 * 64;

  f32x4 acc[4][2];
  #pragma unroll
  for(int i = 0; i < 4; i++)
    #pragma unroll
    for(int j = 0; j < 2; j++) acc[i][j] = (f32x4){0.f, 0.f, 0.f, 0.f};

  auto STAGE = [&](int buf, int k0){
    #pragma unroll
    for(int q = 0; q < 2; q++){
      const size_t so = ((size_t)(q * 64) << 9) + k0;
      const int    dq = dbase + q * 64 * 64;
      gll16(ahsrc + so, &AsH[buf][dq]);
      gll16(alsrc + so, &AsL[buf][dq]);
      gll16(bsrc  + so, &Bs [buf][dq]);
    }
  };
  auto COMPUTE = [&](int buf){
    bf16x8 ah[4][2], al[4][2], bv[2][2];
    #pragma unroll
    for(int i = 0; i < 4; i++)
      #pragma unroll
      for(int kq = 0; kq < 2; kq++){
        int row = wm + i*16 + fr;
        ah[i][kq] = *(const bf16x8*)&AsH[buf][row*64 + (((kq*4 + fg) ^ sw) << 3)];
        al[i][kq] = *(const bf16x8*)&AsL[buf][row*64 + (((kq*4 + fg) ^ sw) << 3)];
      }
    #pragma unroll
    for(int j = 0; j < 2; j++)
      #pragma unroll
      for(int kq = 0; kq < 2; kq++){
        int row = wn + j*16 + fr;
        bv[j][kq] = *(const bf16x8*)&Bs[buf][row*64 + (((kq*4 + fg) ^ sw) << 3)];
      }
    __builtin_amdgcn_s_setprio(1);
    #pragma unroll
    for(int i = 0; i < 4; i++)
      #pragma unroll
      for(int j = 0; j < 2; j++){
        acc[i][j] = __builtin_amdgcn_mfma_f32_16x16x32_bf16(ah[i][0], bv[j][0], acc[i][j], 0, 0, 0);
        acc[i][j] = __builtin_amdgcn_mfma_f32_16x16x32_bf16(al[i][0], bv[j][0], acc[i][j], 0, 0, 0);
        acc[i][j] = __builtin_amdgcn_mfma_f32_16x16x32_bf16(ah[i][1], bv[j][1], acc[i][j], 0, 0, 0);
        acc[i][j] = __builtin_amdgcn_mfma_f32_16x16x32_bf16(al[i][1], bv[j][1], acc[i][j], 0, 0, 0);
      }
    __builtin_amdgcn_s_setprio(0);
  };

  STAGE(0, 0);
  asm volatile("s_waitcnt vmcnt(0)" ::: "memory");
  __builtin_amdgcn_s_barrier();
  #pragma unroll
  for(int it = 0; it < 7; ++it){
    STAGE((it + 1) & 1, (it + 1) * 64);
    asm volatile("s_waitcnt vmcnt(6)" ::: "memory");
    __builtin_amdgcn_s_barrier();
    COMPUTE(it & 1);
    asm volatile("" ::: "memory");
    __builtin_amdgcn_s_barrier();
  }
  asm volatile("s_waitcnt vmcnt(0)" ::: "memory");
  __builtin_amdgcn_s_barrier();
  COMPUTE(1);

  // epilogue: store |acc|, LDS histogram (reuse staging LDS), flush
  __syncthreads();
  unsigned* shh = (unsigned*)&AsH[0][0];   // 16 KB
  for(int i = t; i < NQBIN; i += 512) shh[i] = 0;
  __syncthreads();

  float* rimg = res + (size_t)img * HW;
  #pragma unroll
  for(int i = 0; i < 4; i++)
    #pragma unroll
    for(int j = 0; j < 2; j++){
      f32x4 a = acc[i][j];
      int w  = w0 + wn + j*16 + fr;
      int hp = hp0 + wm + i*16 + fg*4;
      #pragma unroll
      for(int r = 0; r < 4; r++){
        float v = fabsf(a[r]);
        rimg[((size_t)(hp + r) << 9) + w] = v;
        atomicAdd(&shh[min((int)(v * 256.f), NQBIN - 1)], 1u);
      }
    }
  __syncthreads();

  unsigned* hg = qh + (size_t)img * NQBIN;
  for(int i = t; i < NQBIN; i += 512){
    unsigned c = shh[i];
    if(c) atomicAdd(&hg[i], c);
  }
}

// ---- percentiles (linear interp at 3% / 97%) -> (lo, 1/(hi-lo)) ----
__global__ void k_pct(const unsigned* __restrict__ qh, float2* __restrict__ prm){
  int img = blockIdx.x, t = threadIdx.x;
  const unsigned* h = qh + (size_t)img * NQBIN;
  __shared__ unsigned sh[NQBIN];
  for(int i = t; i < NQBIN; i += 256) sh[i] = h[i];
  __syncthreads();
  if(t == 0){
    const unsigned targ[4] = {7864u, 7865u, 254278u, 254279u};
    float v[4]; unsigned cum = 0; int b = 0;
    for(int q = 0; q < 4; q++){
      while(cum + sh[b] <= targ[q]){ cum += sh[b]; ++b; }
      v[q] = (float)b * (1.0f / 256.0f);
    }
    double plo = 0.03 * 262143.0;
    double phi = 0.97 * 262143.0;
    float lo = v[0] + (float)(plo - 7864.0)   * (v[1] - v[0]);
    float hi = v[2] + (float)(phi - 254278.0) * (v[3] - v[2]);
    prm[img] = make_float2(lo, 1.0f / (hi - lo));
  }
}

// ---- in-place normalize: out = (res - lo) * inv * mask ----
__global__ __launch_bounds__(256) void k_norm(float* __restrict__ out, const float* __restrict__ mask,
                                              const float2* __restrict__ prm){
  size_t i4 = (size_t)blockIdx.x * blockDim.x + threadIdx.x;
  const size_t total4 = (size_t)NIMG * HW / 4;
  const size_t step = (size_t)gridDim.x * blockDim.x;
  for(; i4 < total4; i4 += step){
    size_t i = i4 * 4;
    int bc = (int)(i >> 18);
    int bb = bc / 3;
    size_t mi = ((size_t)bb << 18) + (i & 0x3FFFFu);
    float4 r = *(float4*)(out + i);
    float4 m = *(const float4*)(mask + mi);
    float2 p = prm[bc];
    float4 o;
    o.x = (r.x - p.x) * p.y * m.x;
    o.y = (r.y - p.x) * p.y * m.y;
    o.z = (r.z - p.x) * p.y * m.z;
    o.w = (r.w - p.x) * p.y * m.w;
    *(float4*)(out + i) = o;
  }
}

extern "C" void kernel_launch(void* const* d_in, const int* in_sizes, int n_in,
                              void* d_out, int out_size, void* d_ws, size_t ws_size,
                              hipStream_t stream)
{
  const float* x       = (const float*)d_in[0];
  const float* mask    = (const float*)d_in[1];
  const float* fmap_in = (const float*)d_in[2];
  float* out = (float*)d_out;

  const size_t T1_BYTES = (size_t)NIMG * HW * 2;   // 50,331,648 each for t1h and xh
  char* ws = (char*)d_ws;
  unsigned short* t1h = (unsigned short*)ws;                    // [0, 48 MiB)
  unsigned short* xh  = (unsigned short*)(ws + T1_BYTES);       // [48, 96 MiB)
  // aliases (non-overlapping lifetimes):
  unsigned* h1 = (unsigned*)ws;                                 // dead before rowpass writes t1h
  unsigned* h2 = (unsigned*)(ws + (size_t)NIMG * 4096 * 4);
  unsigned* qh = (unsigned*)xh;                                 // used after rowpass read of xh
  char* tail = ws + 2 * T1_BYTES;
  float*          Dir = (float*)tail;                           // 2048 B
  unsigned short* CmH = (unsigned short*)(tail + 2048);         // 512 KB
  unsigned short* CmL = (unsigned short*)(tail + 2048 + 524288);// 512 KB
  char* tail2 = tail + 2048 + 1048576;
  float*  med  = (float*)tail2;
  uint2*  sel1 = (uint2*)(tail2 + 512);
  float2* prm  = (float2*)(tail2 + 1536);

  k_dir<<<512, 256, 0, stream>>>(fmap_in, Dir);
  k_cmat<<<512, 256, 0, stream>>>(Dir, CmH, CmL);

  // 2-pass LDS radix select: median prefix to 24 bits (midpoint, err <= 8e-6)
  hipMemsetAsync(h1, 0, (size_t)NIMG * 4096 * 4 * 2, stream);
  k_p1<<<NIMG * 8, 256, 0, stream>>>(x, h1);
  k_scan1<<<NIMG, 256, 0, stream>>>(h1, sel1);
  k_p2<<<NIMG * 8, 256, 0, stream>>>(x, sel1, h2);
  k_scan_med<<<NIMG, 256, 0, stream>>>(h2, sel1, med);

  // pad+convert once; GEMM passes become pure-copy staging (DMA-able)
  k_prepad<<<(NIMG * HW / 8) / 256, 256, 0, stream>>>(x, mask, med, xh);
  k_rowpass<<<1536, 512, 0, stream>>>(xh, CmH, CmL, t1h);

  hipMemsetAsync(qh, 0, (size_t)NIMG * NQBIN * 4, stream);     // qh aliases xh (now dead)
  k_colpass<<<1536, 512, 0, stream>>>(t1h, CmH, CmL, out, qh);

  k_pct<<<NIMG, 256, 0, stream>>>(qh, prm);
  k_norm<<<2048, 256, 0, stream>>>(out, mask, prm);
}

// Round 10
// 296.244 us; speedup vs baseline: 1.7393x; 1.0690x over previous
//
#include <hip/hip_runtime.h>
#include <math.h>

#define HW 262144     // 512*512
#define NIMG 96       // B*C
#define NQBIN 4096

typedef __attribute__((ext_vector_type(8))) short bf16x8;
typedef __attribute__((ext_vector_type(4))) float f32x4;

// ---- helpers ----
__device__ __forceinline__ unsigned fmap_u(float f){
  unsigned u = __float_as_uint(f);
  return (u & 0x80000000u) ? ~u : (u | 0x80000000u);
}
__device__ __forceinline__ float funmap_u(unsigned u){
  unsigned v = (u & 0x80000000u) ? (u & 0x7fffffffu) : ~u;
  return __uint_as_float(v);
}
__device__ __forceinline__ unsigned bf16rne(float f){
  unsigned u = __float_as_uint(f);
  return (u + 0x7fffu + ((u >> 16) & 1u)) >> 16;
}
__device__ __forceinline__ void split2(float v, unsigned &h, unsigned &l){
  h = bf16rne(v);
  float fh = __uint_as_float(h << 16);
  l = bf16rne(v - fh);
}

// global -> LDS direct DMA, 16 B per lane. LDS dest = wave-uniform base + lane*16.
typedef __attribute__((address_space(3))) unsigned lds_u;
typedef const __attribute__((address_space(1))) unsigned glb_u;
__device__ __forceinline__ void gll16(const void* g, void* l){
  __builtin_amdgcn_global_load_lds((glb_u*)g, (lds_u*)l, 16, 0, 0);
}

// ---- Dir[n] = Re( ifft(filter_map row 0) )[n], computed in double ----
__global__ void k_dir(const float* __restrict__ fmap_in, float* __restrict__ Dir){
  int n = blockIdx.x;
  int t = threadIdx.x;
  double s = 0.0;
  for(int c = t; c < 512; c += 256){
    int a = (c * n) & 511;
    s += (double)fmap_in[c] * cos(6.283185307179586476925287 * (double)a / 512.0);
  }
  __shared__ double red[256];
  red[t] = s; __syncthreads();
  for(int off = 128; off; off >>= 1){
    if(t < off) red[t] += red[t + off];
    __syncthreads();
  }
  if(t == 0) Dir[n] = (float)(red[0] / 512.0);
}

// ---- Cm[a][b] = Dir[(a-b)&511], split bf16 hi/lo (1 MB, L2-resident) ----
__global__ void k_cmat(const float* __restrict__ Dir, unsigned short* __restrict__ CmH,
                       unsigned short* __restrict__ CmL){
  int a = blockIdx.x;
  for(int b = threadIdx.x; b < 512; b += 256){
    float d = Dir[(a - b) & 511];
    unsigned h, l; split2(d, h, l);
    CmH[(size_t)a * 512 + b] = (unsigned short)h;
    CmL[(size_t)a * 512 + b] = (unsigned short)l;
  }
}

// ==== exact-to-24-bits median via 2-pass LDS radix select (12 / 12 bits) ====
__global__ __launch_bounds__(256) void k_p1(const float* __restrict__ x, unsigned* __restrict__ h){
  __shared__ unsigned sh[4096];
  const int img  = blockIdx.x >> 3;
  const int part = blockIdx.x & 7;
  const float4* p = (const float4*)(x + (size_t)img * HW + (size_t)part * 32768);
  for(int i = threadIdx.x; i < 4096; i += 256) sh[i] = 0;
  __syncthreads();
  for(int i = threadIdx.x; i < 8192; i += 256){
    float4 v = p[i];
    atomicAdd(&sh[fmap_u(v.x) >> 20], 1u);
    atomicAdd(&sh[fmap_u(v.y) >> 20], 1u);
    atomicAdd(&sh[fmap_u(v.z) >> 20], 1u);
    atomicAdd(&sh[fmap_u(v.w) >> 20], 1u);
  }
  __syncthreads();
  unsigned* hh = h + (size_t)img * 4096;
  for(int i = threadIdx.x; i < 4096; i += 256){
    unsigned c = sh[i];
    if(c) atomicAdd(&hh[i], c);
  }
}

__global__ __launch_bounds__(256) void k_p2(const float* __restrict__ x, const uint2* __restrict__ sel1,
                                            unsigned* __restrict__ h){
  __shared__ unsigned sh[4096];
  const int img  = blockIdx.x >> 3;
  const int part = blockIdx.x & 7;
  const unsigned b1 = sel1[img].x;
  const float4* p = (const float4*)(x + (size_t)img * HW + (size_t)part * 32768);
  for(int i = threadIdx.x; i < 4096; i += 256) sh[i] = 0;
  __syncthreads();
  for(int i = threadIdx.x; i < 8192; i += 256){
    float4 v = p[i];
    unsigned u;
    u = fmap_u(v.x); if((u >> 20) == b1) atomicAdd(&sh[(u >> 8) & 0xFFFu], 1u);
    u = fmap_u(v.y); if((u >> 20) == b1) atomicAdd(&sh[(u >> 8) & 0xFFFu], 1u);
    u = fmap_u(v.z); if((u >> 20) == b1) atomicAdd(&sh[(u >> 8) & 0xFFFu], 1u);
    u = fmap_u(v.w); if((u >> 20) == b1) atomicAdd(&sh[(u >> 8) & 0xFFFu], 1u);
  }
  __syncthreads();
  unsigned* hh = h + (size_t)img * 4096;
  for(int i = threadIdx.x; i < 4096; i += 256){
    unsigned c = sh[i];
    if(c) atomicAdd(&hh[i], c);
  }
}

__global__ void k_scan1(const unsigned* __restrict__ h, uint2* __restrict__ osel){
  int img = blockIdx.x, t = threadIdx.x;
  const unsigned* hh = h + (size_t)img * 4096;
  __shared__ unsigned csum[256];
  unsigned s = 0;
  for(int j = 0; j < 16; j++) s += hh[t * 16 + j];
  csum[t] = s; __syncthreads();
  if(t == 0){
    unsigned k = 131071u, cum = 0; int chunk = 0;
    for(; chunk < 256; ++chunk){ if(cum + csum[chunk] > k) break; cum += csum[chunk]; }
    int b = chunk * 16;
    for(;; ++b){ unsigned c = hh[b]; if(cum + c > k) break; cum += c; }
    osel[img] = make_uint2((unsigned)b, k - cum);
  }
}

__global__ void k_scan_med(const unsigned* __restrict__ h, const uint2* __restrict__ sel1,
                           float* __restrict__ med){
  int img = blockIdx.x, t = threadIdx.x;
  const unsigned* hh = h + (size_t)img * 4096;
  __shared__ unsigned csum[256];
  unsigned s = 0;
  for(int j = 0; j < 16; j++) s += hh[t * 16 + j];
  csum[t] = s; __syncthreads();
  if(t == 0){
    unsigned k = sel1[img].y, cum = 0; int chunk = 0;
    for(; chunk < 256; ++chunk){ if(cum + csum[chunk] > k) break; cum += csum[chunk]; }
    int b = chunk * 16;
    for(;; ++b){ unsigned c = hh[b]; if(cum + c > k) break; cum += c; }
    unsigned u = (sel1[img].x << 20) | ((unsigned)b << 8) | 128u;
    med[img] = funmap_u(u) + 0.2f;
  }
}

// ==== MFMA row pass: fused pad+convert (T14 reg-staged A) + DMA B, counted vmcnt ====
// t1T[img][n][h] = bf16( sum_k (mask?x:med)[r][k] * Cm[n][k] )
__global__ __launch_bounds__(512, 1) void k_rowpass(
    const float* __restrict__ x, const float* __restrict__ mask,
    const float* __restrict__ med,
    const unsigned short* __restrict__ CmH, const unsigned short* __restrict__ CmL,
    unsigned short* __restrict__ t1h)
{
  __shared__ __align__(16) unsigned short As [2][8192];
  __shared__ __align__(16) unsigned short BsH[2][8192];
  __shared__ __align__(16) unsigned short BsL[2][8192];

  // XCD swizzle: 4 sibling n-blocks (same x rows) on the same XCD
  const int b    = blockIdx.x;           // 0..1535
  const int xcd  = b & 7;
  const int i8   = b >> 3;               // 0..191
  const int rblk = xcd * 48 + (i8 >> 2); // 0..383
  const int nblk = i8 & 3;
  const int r0 = rblk * 128;
  const int n0 = nblk * 128;
  const int bc = r0 >> 9;
  const int bb = bc / 3;
  const float mv = med[bc];

  const int t    = threadIdx.x;
  const int lane = t & 63;
  const int wv   = t >> 6;               // 0..7
  const int wm   = (wv >> 2) * 64;
  const int wn   = (wv & 3) * 32;
  const int fr   = lane & 15;
  const int fg   = lane >> 4;
  const int sw   = lane & 7;

  // A reg-staging: thread -> row t>>2, 16 cols at (t&3)*16
  const int srow = t >> 2;
  const int sc   = (t & 3) << 4;
  const float* xr = x    + ((size_t)(r0 + srow) << 9) + sc;
  const float* mr = mask + (size_t)bb * HW + ((size_t)((r0 + srow) & 511) << 9) + sc;

  // B DMA mapping: wave wv + q cover rows [q*64 + wv*8, +8); lane l -> row +(l>>3), src blk (l&7)^(l>>3)
  const int drow = lane >> 3;
  const int dblk = (lane & 7) ^ drow;
  const unsigned short* bhsrc = CmH + ((size_t)(n0 + wv*8 + drow) << 9) + dblk * 8;
  const unsigned short* blsrc = CmL + ((size_t)(n0 + wv*8 + drow) << 9) + dblk * 8;
  const int dbase = wv * 8 * 64;

  f32x4 acc[4][2];
  #pragma unroll
  for(int i = 0; i < 4; i++)
    #pragma unroll
    for(int j = 0; j < 2; j++) acc[i][j] = (f32x4){0.f, 0.f, 0.f, 0.f};

  float4 px[4], pm[4];

  auto ALOAD = [&](int k0){
    #pragma unroll
    for(int q = 0; q < 4; q++){
      px[q] = *(const float4*)(xr + k0 + q * 4);
      pm[q] = *(const float4*)(mr + k0 + q * 4);
    }
  };
  auto BDMA = [&](int buf, int k0){
    #pragma unroll
    for(int q = 0; q < 2; q++){
      const size_t so = ((size_t)(q * 64) << 9) + k0;
      const int    dq = dbase + q * 4096;
      gll16(bhsrc + so, &BsH[buf][dq]);
      gll16(blsrc + so, &BsL[buf][dq]);
    }
  };
  auto ACONV = [&](int buf){
    unsigned hp[8];
    #pragma unroll
    for(int q = 0; q < 4; q++){
      unsigned h0 = bf16rne((pm[q].x != 0.f) ? px[q].x : mv);
      unsigned h1 = bf16rne((pm[q].y != 0.f) ? px[q].y : mv);
      unsigned h2 = bf16rne((pm[q].z != 0.f) ? px[q].z : mv);
      unsigned h3 = bf16rne((pm[q].w != 0.f) ? px[q].w : mv);
      hp[q*2]   = (h1 << 16) | h0;
      hp[q*2+1] = (h3 << 16) | h2;
    }
    const int b0 = (t & 3) * 2;
    *(uint4*)&As[buf][srow * 64 + (( b0      ^ (srow & 7)) << 3)] = make_uint4(hp[0], hp[1], hp[2], hp[3]);
    *(uint4*)&As[buf][srow * 64 + (((b0 | 1) ^ (srow & 7)) << 3)] = make_uint4(hp[4], hp[5], hp[6], hp[7]);
  };
  auto COMPUTE = [&](int buf){
    bf16x8 af[4][2], bh[2][2], bl[2][2];
    #pragma unroll
    for(int i = 0; i < 4; i++)
      #pragma unroll
      for(int kq = 0; kq < 2; kq++){
        int row = wm + i*16 + fr;
        af[i][kq] = *(const bf16x8*)&As[buf][row*64 + (((kq*4 + fg) ^ sw) << 3)];
      }
    #pragma unroll
    for(int j = 0; j < 2; j++)
      #pragma unroll
      for(int kq = 0; kq < 2; kq++){
        int row = wn + j*16 + fr;
        bh[j][kq] = *(const bf16x8*)&BsH[buf][row*64 + (((kq*4 + fg) ^ sw) << 3)];
        bl[j][kq] = *(const bf16x8*)&BsL[buf][row*64 + (((kq*4 + fg) ^ sw) << 3)];
      }
    __builtin_amdgcn_s_setprio(1);
    #pragma unroll
    for(int i = 0; i < 4; i++)
      #pragma unroll
      for(int j = 0; j < 2; j++){
        acc[i][j] = __builtin_amdgcn_mfma_f32_16x16x32_bf16(af[i][0], bh[j][0], acc[i][j], 0, 0, 0);
        acc[i][j] = __builtin_amdgcn_mfma_f32_16x16x32_bf16(af[i][0], bl[j][0], acc[i][j], 0, 0, 0);
        acc[i][j] = __builtin_amdgcn_mfma_f32_16x16x32_bf16(af[i][1], bh[j][1], acc[i][j], 0, 0, 0);
        acc[i][j] = __builtin_amdgcn_mfma_f32_16x16x32_bf16(af[i][1], bl[j][1], acc[i][j], 0, 0, 0);
      }
    __builtin_amdgcn_s_setprio(0);
  };

  // prologue: tile 0
  ALOAD(0); BDMA(0, 0);
  asm volatile("s_waitcnt vmcnt(4)" ::: "memory");   // A-loads done (4 gll16 outstanding)
  ACONV(0);
  asm volatile("s_waitcnt vmcnt(0) lgkmcnt(0)" ::: "memory");
  __builtin_amdgcn_sched_barrier(0);
  __builtin_amdgcn_s_barrier();

  #pragma unroll
  for(int it = 0; it < 7; ++it){
    ALOAD((it + 1) * 64);                 // next tile A -> regs (flies under compute)
    BDMA((it + 1) & 1, (it + 1) * 64);    // next tile B -> LDS DMA
    COMPUTE(it & 1);
    asm volatile("s_waitcnt vmcnt(4)" ::: "memory");   // A-loads landed
    ACONV((it + 1) & 1);
    asm volatile("s_waitcnt vmcnt(0) lgkmcnt(0)" ::: "memory");
    __builtin_amdgcn_sched_barrier(0);
    __builtin_amdgcn_s_barrier();
  }
  COMPUTE(1);

  // epilogue: t1 transposed single bf16
  const int img = r0 >> 9;
  const int hb  = r0 & 511;
  #pragma unroll
  for(int i = 0; i < 4; i++)
    #pragma unroll
    for(int j = 0; j < 2; j++){
      f32x4 a = acc[i][j];
      unsigned b0 = bf16rne(a[0]), b1 = bf16rne(a[1]), b2 = bf16rne(a[2]), b3 = bf16rne(a[3]);
      int n = n0 + wn + j*16 + fr;
      int h = hb + wm + i*16 + fg*4;
      *(uint2*)&t1h[(size_t)img * HW + ((size_t)n << 9) + h] =
          make_uint2((b1<<16)|b0, (b3<<16)|b2);
    }
}

// ==== MFMA col pass: single-bf16 A (CmH only), 64 KB LDS -> 2 blocks/CU; fused q-hist ====
__global__ __launch_bounds__(512, 4) void k_colpass(
    const unsigned short* __restrict__ t1h,
    const unsigned short* __restrict__ CmH,
    float* __restrict__ res, unsigned* __restrict__ qh)
{
  __shared__ __align__(16) unsigned short AsH[2][8192];
  __shared__ __align__(16) unsigned short Bs [2][8192];

  // XCD swizzle: all 16 blocks of one image on the same XCD (t1 image L2-resident)
  const int b    = blockIdx.x;           // 0..1535
  const int xcd  = b & 7;
  const int i8   = b >> 3;               // 0..191
  const int img  = xcd * 12 + (i8 >> 4);
  const int r16  = i8 & 15;
  const int hp0  = (r16 >> 2) * 128;
  const int w0   = (r16 & 3) * 128;

  const int t    = threadIdx.x;
  const int lane = t & 63;
  const int wv   = t >> 6;
  const int wm   = (wv >> 2) * 64;
  const int wn   = (wv & 3) * 32;
  const int fr   = lane & 15;
  const int fg   = lane >> 4;
  const int sw   = lane & 7;

  const int drow = lane >> 3;
  const int dblk = (lane & 7) ^ drow;
  const unsigned short* ahsrc = CmH + ((size_t)(hp0 + wv*8 + drow) << 9) + dblk * 8;
  const unsigned short* bsrc  = t1h + (size_t)img * HW + ((size_t)(w0 + wv*8 + drow) << 9) + dblk * 8;
  const int dbase = wv * 8 * 64;

  f32x4 acc[4][2];
  #pragma unroll
  for(int i = 0; i < 4; i++)
    #pragma unroll
    for(int j = 0; j < 2; j++) acc[i][j] = (f32x4){0.f, 0.f, 0.f, 0.f};

  auto STAGE = [&](int buf, int k0){
    #pragma unroll
    for(int q = 0; q < 2; q++){
      const size_t so = ((size_t)(q * 64) << 9) + k0;
      const int    dq = dbase + q * 4096;
      gll16(ahsrc + so, &AsH[buf][dq]);
      gll16(bsrc  + so, &Bs [buf][dq]);
    }
  };
  auto COMPUTE = [&](int buf){
    bf16x8 ah[4][2], bv[2][2];
    #pragma unroll
    for(int i = 0; i < 4; i++)
      #pragma unroll
      for(int kq = 0; kq < 2; kq++){
        int row = wm + i*16 + fr;
        ah[i][kq] = *(const bf16x8*)&AsH[buf][row*64 + (((kq*4 + fg) ^ sw) << 3)];
      }
    #pragma unroll
    for(int j = 0; j < 2; j++)
      #pragma unroll
      for(int kq = 0; kq < 2; kq++){
        int row = wn + j*16 + fr;
        bv[j][kq] = *(const bf16x8*)&Bs[buf][row*64 + (((kq*4 + fg) ^ sw) << 3)];
      }
    __builtin_amdgcn_s_setprio(1);
    #pragma unroll
    for(int i = 0; i < 4; i++)
      #pragma unroll
      for(int j = 0; j < 2; j++){
        acc[i][j] = __builtin_amdgcn_mfma_f32_16x16x32_bf16(ah[i][0], bv[j][0], acc[i][j], 0, 0, 0);
        acc[i][j] = __builtin_amdgcn_mfma_f32_16x16x32_bf16(ah[i][1], bv[j][1], acc[i][j], 0, 0, 0);
      }
    __builtin_amdgcn_s_setprio(0);
  };

  STAGE(0, 0);
  asm volatile("s_waitcnt vmcnt(0)" ::: "memory");
  __builtin_amdgcn_s_barrier();
  #pragma unroll
  for(int it = 0; it < 7; ++it){
    STAGE((it + 1) & 1, (it + 1) * 64);
    asm volatile("s_waitcnt vmcnt(4)" ::: "memory");   // drain tile it, keep it+1 in flight
    __builtin_amdgcn_s_barrier();
    COMPUTE(it & 1);
    asm volatile("" ::: "memory");
    __builtin_amdgcn_s_barrier();
  }
  asm volatile("s_waitcnt vmcnt(0)" ::: "memory");
  __builtin_amdgcn_s_barrier();
  COMPUTE(1);

  // epilogue: store |acc|, LDS histogram (reuse staging LDS), flush
  __syncthreads();
  unsigned* shh = (unsigned*)&AsH[0][0];   // 16 KB of 32 KB
  for(int i = t; i < NQBIN; i += 512) shh[i] = 0;
  __syncthreads();

  float* rimg = res + (size_t)img * HW;
  #pragma unroll
  for(int i = 0; i < 4; i++)
    #pragma unroll
    for(int j = 0; j < 2; j++){
      f32x4 a = acc[i][j];
      int w  = w0 + wn + j*16 + fr;
      int hp = hp0 + wm + i*16 + fg*4;
      #pragma unroll
      for(int r = 0; r < 4; r++){
        float v = fabsf(a[r]);
        rimg[((size_t)(hp + r) << 9) + w] = v;
        atomicAdd(&shh[min((int)(v * 256.f), NQBIN - 1)], 1u);
      }
    }
  __syncthreads();

  unsigned* hg = qh + (size_t)img * NQBIN;
  for(int i = t; i < NQBIN; i += 512){
    unsigned c = shh[i];
    if(c) atomicAdd(&hg[i], c);
  }
}

// ---- percentiles (linear interp at 3% / 97%) -> (lo, 1/(hi-lo)) ----
__global__ void k_pct(const unsigned* __restrict__ qh, float2* __restrict__ prm){
  int img = blockIdx.x, t = threadIdx.x;
  const unsigned* h = qh + (size_t)img * NQBIN;
  __shared__ unsigned sh[NQBIN];
  for(int i = t; i < NQBIN; i += 256) sh[i] = h[i];
  __syncthreads();
  if(t == 0){
    const unsigned targ[4] = {7864u, 7865u, 254278u, 254279u};
    float v[4]; unsigned cum = 0; int b = 0;
    for(int q = 0; q < 4; q++){
      while(cum + sh[b] <= targ[q]){ cum += sh[b]; ++b; }
      v[q] = (float)b * (1.0f / 256.0f);
    }
    double plo = 0.03 * 262143.0;
    double phi = 0.97 * 262143.0;
    float lo = v[0] + (float)(plo - 7864.0)   * (v[1] - v[0]);
    float hi = v[2] + (float)(phi - 254278.0) * (v[3] - v[2]);
    prm[img] = make_float2(lo, 1.0f / (hi - lo));
  }
}

// ---- in-place normalize: out = (res - lo) * inv * mask ----
__global__ __launch_bounds__(256) void k_norm(float* __restrict__ out, const float* __restrict__ mask,
                                              const float2* __restrict__ prm){
  size_t i4 = (size_t)blockIdx.x * blockDim.x + threadIdx.x;
  const size_t total4 = (size_t)NIMG * HW / 4;
  const size_t step = (size_t)gridDim.x * blockDim.x;
  for(; i4 < total4; i4 += step){
    size_t i = i4 * 4;
    int bc = (int)(i >> 18);
    int bb = bc / 3;
    size_t mi = ((size_t)bb << 18) + (i & 0x3FFFFu);
    float4 r = *(float4*)(out + i);
    float4 m = *(const float4*)(mask + mi);
    float2 p = prm[bc];
    float4 o;
    o.x = (r.x - p.x) * p.y * m.x;
    o.y = (r.y - p.x) * p.y * m.y;
    o.z = (r.z - p.x) * p.y * m.z;
    o.w = (r.w - p.x) * p.y * m.w;
    *(float4*)(out + i) = o;
  }
}

extern "C" void kernel_launch(void* const* d_in, const int* in_sizes, int n_in,
                              void* d_out, int out_size, void* d_ws, size_t ws_size,
                              hipStream_t stream)
{
  const float* x       = (const float*)d_in[0];
  const float* mask    = (const float*)d_in[1];
  const float* fmap_in = (const float*)d_in[2];
  float* out = (float*)d_out;

  const size_t T1_BYTES = (size_t)NIMG * HW * 2;   // 48 MiB (bf16 t1T)
  char* ws = (char*)d_ws;
  unsigned short* t1h = (unsigned short*)ws;                    // lives rowpass..colpass
  // aliases with non-overlapping lifetimes:
  unsigned* h1 = (unsigned*)ws;                                 // dead before rowpass writes t1h
  unsigned* h2 = (unsigned*)(ws + (size_t)NIMG * 4096 * 4);
  unsigned* qh = (unsigned*)(ws + T1_BYTES);                    // own region (1.5 MB)
  char* tail = ws + T1_BYTES + (size_t)NIMG * NQBIN * 4;
  float*          Dir = (float*)tail;                           // 2048 B
  unsigned short* CmH = (unsigned short*)(tail + 2048);         // 512 KB
  unsigned short* CmL = (unsigned short*)(tail + 2048 + 524288);// 512 KB
  char* tail2 = tail + 2048 + 1048576;
  float*  med  = (float*)tail2;
  uint2*  sel1 = (uint2*)(tail2 + 512);
  float2* prm  = (float2*)(tail2 + 1536);

  k_dir<<<512, 256, 0, stream>>>(fmap_in, Dir);
  k_cmat<<<512, 256, 0, stream>>>(Dir, CmH, CmL);

  // 2-pass LDS radix select: median prefix to 24 bits (midpoint, err <= 8e-6)
  hipMemsetAsync(h1, 0, (size_t)NIMG * 4096 * 4 * 2, stream);
  k_p1<<<NIMG * 8, 256, 0, stream>>>(x, h1);
  k_scan1<<<NIMG, 256, 0, stream>>>(h1, sel1);
  k_p2<<<NIMG * 8, 256, 0, stream>>>(x, sel1, h2);
  k_scan_med<<<NIMG, 256, 0, stream>>>(h2, sel1, med);

  hipMemsetAsync(qh, 0, (size_t)NIMG * NQBIN * 4, stream);
  k_rowpass<<<1536, 512, 0, stream>>>(x, mask, med, CmH, CmL, t1h);
  k_colpass<<<1536, 512, 0, stream>>>(t1h, CmH, out, qh);

  k_pct<<<NIMG, 256, 0, stream>>>(qh, prm);
  k_norm<<<2048, 256, 0, stream>>>(out, mask, prm);
}

// Round 12
// 253.234 us; speedup vs baseline: 2.0347x; 1.1698x over previous
//
#include <hip/hip_runtime.h>
#include <math.h>

#define HW 262144     // 512*512
#define NIMG 96       // B*C
#define NQBIN 4096

typedef __attribute__((ext_vector_type(8))) short bf16x8;
typedef __attribute__((ext_vector_type(4))) float f32x4;

// ---- helpers ----
__device__ __forceinline__ unsigned fmap_u(float f){
  unsigned u = __float_as_uint(f);
  return (u & 0x80000000u) ? ~u : (u | 0x80000000u);
}
__device__ __forceinline__ float funmap_u(unsigned u){
  unsigned v = (u & 0x80000000u) ? (u & 0x7fffffffu) : ~u;
  return __uint_as_float(v);
}
__device__ __forceinline__ unsigned bf16rne(float f){
  unsigned u = __float_as_uint(f);
  return (u + 0x7fffu + ((u >> 16) & 1u)) >> 16;
}

// global -> LDS direct DMA, 16 B per lane. LDS dest = wave-uniform base + lane*16.
typedef __attribute__((address_space(3))) unsigned lds_u;
typedef const __attribute__((address_space(1))) unsigned glb_u;
__device__ __forceinline__ void gll16(const void* g, void* l){
  __builtin_amdgcn_global_load_lds((glb_u*)g, (lds_u*)l, 16, 0, 0);
}

// ---- Dir[n] = Re( ifft(filter_map row 0) )[n], computed in double ----
__global__ void k_dir(const float* __restrict__ fmap_in, float* __restrict__ Dir){
  int n = blockIdx.x;
  int t = threadIdx.x;
  double s = 0.0;
  for(int c = t; c < 512; c += 256){
    int a = (c * n) & 511;
    s += (double)fmap_in[c] * cos(6.283185307179586476925287 * (double)a / 512.0);
  }
  __shared__ double red[256];
  red[t] = s; __syncthreads();
  for(int off = 128; off; off >>= 1){
    if(t < off) red[t] += red[t + off];
    __syncthreads();
  }
  if(t == 0) Dir[n] = (float)(red[0] / 512.0);
}

// ---- Cm[a][b] = bf16( Dir[(a-b)&511] )  (512 KB, L2-resident)
// r10 evidence: dropping the low-split leaves absmax unchanged.
__global__ void k_cmat(const float* __restrict__ Dir, unsigned short* __restrict__ CmH){
  int a = blockIdx.x;
  for(int b = threadIdx.x; b < 512; b += 256){
    float d = Dir[(a - b) & 511];
    CmH[(size_t)a * 512 + b] = (unsigned short)bf16rne(d);
  }
}

// ==== exact-to-24-bits median via 2-pass LDS radix select (12 / 12 bits) ====
__global__ __launch_bounds__(256) void k_p1(const float* __restrict__ x, unsigned* __restrict__ h){
  __shared__ unsigned sh[4096];
  const int img  = blockIdx.x >> 3;
  const int part = blockIdx.x & 7;
  const float4* p = (const float4*)(x + (size_t)img * HW + (size_t)part * 32768);
  for(int i = threadIdx.x; i < 4096; i += 256) sh[i] = 0;
  __syncthreads();
  for(int i = threadIdx.x; i < 8192; i += 256){
    float4 v = p[i];
    atomicAdd(&sh[fmap_u(v.x) >> 20], 1u);
    atomicAdd(&sh[fmap_u(v.y) >> 20], 1u);
    atomicAdd(&sh[fmap_u(v.z) >> 20], 1u);
    atomicAdd(&sh[fmap_u(v.w) >> 20], 1u);
  }
  __syncthreads();
  unsigned* hh = h + (size_t)img * 4096;
  for(int i = threadIdx.x; i < 4096; i += 256){
    unsigned c = sh[i];
    if(c) atomicAdd(&hh[i], c);
  }
}

__global__ __launch_bounds__(256) void k_p2(const float* __restrict__ x, const uint2* __restrict__ sel1,
                                            unsigned* __restrict__ h){
  __shared__ unsigned sh[4096];
  const int img  = blockIdx.x >> 3;
  const int part = blockIdx.x & 7;
  const unsigned b1 = sel1[img].x;
  const float4* p = (const float4*)(x + (size_t)img * HW + (size_t)part * 32768);
  for(int i = threadIdx.x; i < 4096; i += 256) sh[i] = 0;
  __syncthreads();
  for(int i = threadIdx.x; i < 8192; i += 256){
    float4 v = p[i];
    unsigned u;
    u = fmap_u(v.x); if((u >> 20) == b1) atomicAdd(&sh[(u >> 8) & 0xFFFu], 1u);
    u = fmap_u(v.y); if((u >> 20) == b1) atomicAdd(&sh[(u >> 8) & 0xFFFu], 1u);
    u = fmap_u(v.z); if((u >> 20) == b1) atomicAdd(&sh[(u >> 8) & 0xFFFu], 1u);
    u = fmap_u(v.w); if((u >> 20) == b1) atomicAdd(&sh[(u >> 8) & 0xFFFu], 1u);
  }
  __syncthreads();
  unsigned* hh = h + (size_t)img * 4096;
  for(int i = threadIdx.x; i < 4096; i += 256){
    unsigned c = sh[i];
    if(c) atomicAdd(&hh[i], c);
  }
}

__global__ void k_scan1(const unsigned* __restrict__ h, uint2* __restrict__ osel){
  int img = blockIdx.x, t = threadIdx.x;
  const unsigned* hh = h + (size_t)img * 4096;
  __shared__ unsigned csum[256];
  unsigned s = 0;
  for(int j = 0; j < 16; j++) s += hh[t * 16 + j];
  csum[t] = s; __syncthreads();
  if(t == 0){
    unsigned k = 131071u, cum = 0; int chunk = 0;
    for(; chunk < 256; ++chunk){ if(cum + csum[chunk] > k) break; cum += csum[chunk]; }
    int b = chunk * 16;
    for(;; ++b){ unsigned c = hh[b]; if(cum + c > k) break; cum += c; }
    osel[img] = make_uint2((unsigned)b, k - cum);
  }
}

__global__ void k_scan_med(const unsigned* __restrict__ h, const uint2* __restrict__ sel1,
                           float* __restrict__ med){
  int img = blockIdx.x, t = threadIdx.x;
  const unsigned* hh = h + (size_t)img * 4096;
  __shared__ unsigned csum[256];
  unsigned s = 0;
  for(int j = 0; j < 16; j++) s += hh[t * 16 + j];
  csum[t] = s; __syncthreads();
  if(t == 0){
    unsigned k = sel1[img].y, cum = 0; int chunk = 0;
    for(; chunk < 256; ++chunk){ if(cum + csum[chunk] > k) break; cum += csum[chunk]; }
    int b = chunk * 16;
    for(;; ++b){ unsigned c = hh[b]; if(cum + c > k) break; cum += c; }
    unsigned u = (sel1[img].x << 20) | ((unsigned)b << 8) | 128u;
    med[img] = funmap_u(u) + 0.2f;
  }
}

// ==== MFMA row pass: fused pad+convert A (reg-staged) + DMA B, 64 KB LDS (2 blk/CU) ====
// t1T[img][n][h] = bf16( sum_k (mask?x:med)[r][k] * Cm[n][k] )
__global__ __launch_bounds__(512, 4) void k_rowpass(
    const float* __restrict__ x, const float* __restrict__ mask,
    const float* __restrict__ med,
    const unsigned short* __restrict__ CmH,
    unsigned short* __restrict__ t1h)
{
  __shared__ __align__(16) unsigned short As [2][8192];
  __shared__ __align__(16) unsigned short BsH[2][8192];

  // XCD swizzle: 4 sibling n-blocks (same x rows) on the same XCD
  const int b    = blockIdx.x;           // 0..1535
  const int xcd  = b & 7;
  const int i8   = b >> 3;               // 0..191
  const int rblk = xcd * 48 + (i8 >> 2); // 0..383
  const int nblk = i8 & 3;
  const int r0 = rblk * 128;
  const int n0 = nblk * 128;
  const int bc = r0 >> 9;
  const int bb = bc / 3;
  const float mv = med[bc];

  const int t    = threadIdx.x;
  const int lane = t & 63;
  const int wv   = t >> 6;               // 0..7
  const int wm   = (wv >> 2) * 64;
  const int wn   = (wv & 3) * 32;
  const int fr   = lane & 15;
  const int fg   = lane >> 4;
  const int sw   = lane & 7;

  // A reg-staging: thread -> row t>>2, 16 cols at (t&3)*16
  const int srow = t >> 2;
  const int sc   = (t & 3) << 4;
  const float* xr = x    + ((size_t)(r0 + srow) << 9) + sc;
  const float* mr = mask + (size_t)bb * HW + ((size_t)((r0 + srow) & 511) << 9) + sc;

  // B DMA mapping: wave wv + q cover rows [q*64 + wv*8, +8); lane l -> row +(l>>3), src blk (l&7)^(l>>3)
  const int drow = lane >> 3;
  const int dblk = (lane & 7) ^ drow;
  const unsigned short* bhsrc = CmH + ((size_t)(n0 + wv*8 + drow) << 9) + dblk * 8;
  const int dbase = wv * 8 * 64;

  f32x4 acc[4][2];
  #pragma unroll
  for(int i = 0; i < 4; i++)
    #pragma unroll
    for(int j = 0; j < 2; j++) acc[i][j] = (f32x4){0.f, 0.f, 0.f, 0.f};

  float4 px[4], pm[4];

  auto ALOAD = [&](int k0){
    #pragma unroll
    for(int q = 0; q < 4; q++){
      px[q] = *(const float4*)(xr + k0 + q * 4);
      pm[q] = *(const float4*)(mr + k0 + q * 4);
    }
  };
  auto BDMA = [&](int buf, int k0){
    #pragma unroll
    for(int q = 0; q < 2; q++){
      const size_t so = ((size_t)(q * 64) << 9) + k0;
      const int    dq = dbase + q * 4096;
      gll16(bhsrc + so, &BsH[buf][dq]);
    }
  };
  auto ACONV = [&](int buf){
    unsigned hp[8];
    #pragma unroll
    for(int q = 0; q < 4; q++){
      unsigned h0 = bf16rne((pm[q].x != 0.f) ? px[q].x : mv);
      unsigned h1 = bf16rne((pm[q].y != 0.f) ? px[q].y : mv);
      unsigned h2 = bf16rne((pm[q].z != 0.f) ? px[q].z : mv);
      unsigned h3 = bf16rne((pm[q].w != 0.f) ? px[q].w : mv);
      hp[q*2]   = (h1 << 16) | h0;
      hp[q*2+1] = (h3 << 16) | h2;
    }
    const int b0 = (t & 3) * 2;
    *(uint4*)&As[buf][srow * 64 + (( b0      ^ (srow & 7)) << 3)] = make_uint4(hp[0], hp[1], hp[2], hp[3]);
    *(uint4*)&As[buf][srow * 64 + (((b0 | 1) ^ (srow & 7)) << 3)] = make_uint4(hp[4], hp[5], hp[6], hp[7]);
  };
  auto COMPUTE = [&](int buf){
    bf16x8 af[4][2], bh[2][2];
    #pragma unroll
    for(int i = 0; i < 4; i++)
      #pragma unroll
      for(int kq = 0; kq < 2; kq++){
        int row = wm + i*16 + fr;
        af[i][kq] = *(const bf16x8*)&As[buf][row*64 + (((kq*4 + fg) ^ sw) << 3)];
      }
    #pragma unroll
    for(int j = 0; j < 2; j++)
      #pragma unroll
      for(int kq = 0; kq < 2; kq++){
        int row = wn + j*16 + fr;
        bh[j][kq] = *(const bf16x8*)&BsH[buf][row*64 + (((kq*4 + fg) ^ sw) << 3)];
      }
    __builtin_amdgcn_s_setprio(1);
    #pragma unroll
    for(int i = 0; i < 4; i++)
      #pragma unroll
      for(int j = 0; j < 2; j++){
        acc[i][j] = __builtin_amdgcn_mfma_f32_16x16x32_bf16(af[i][0], bh[j][0], acc[i][j], 0, 0, 0);
        acc[i][j] = __builtin_amdgcn_mfma_f32_16x16x32_bf16(af[i][1], bh[j][1], acc[i][j], 0, 0, 0);
      }
    __builtin_amdgcn_s_setprio(0);
  };

  // prologue: tile 0 (8 A-loads then 2 B-DMA outstanding)
  ALOAD(0); BDMA(0, 0);
  asm volatile("s_waitcnt vmcnt(2)" ::: "memory");   // A-loads done
  ACONV(0);
  asm volatile("s_waitcnt vmcnt(0) lgkmcnt(0)" ::: "memory");
  __builtin_amdgcn_sched_barrier(0);
  __builtin_amdgcn_s_barrier();

  #pragma unroll
  for(int it = 0; it < 7; ++it){
    ALOAD((it + 1) * 64);                 // next tile A -> regs (flies under compute)
    BDMA((it + 1) & 1, (it + 1) * 64);    // next tile B -> LDS DMA
    COMPUTE(it & 1);
    asm volatile("s_waitcnt vmcnt(2)" ::: "memory");   // A-loads landed, B-DMA may fly
    ACONV((it + 1) & 1);
    asm volatile("s_waitcnt vmcnt(0) lgkmcnt(0)" ::: "memory");
    __builtin_amdgcn_sched_barrier(0);
    __builtin_amdgcn_s_barrier();
  }
  COMPUTE(1);

  // epilogue: t1 transposed single bf16
  const int img = r0 >> 9;
  const int hb  = r0 & 511;
  #pragma unroll
  for(int i = 0; i < 4; i++)
    #pragma unroll
    for(int j = 0; j < 2; j++){
      f32x4 a = acc[i][j];
      unsigned b0 = bf16rne(a[0]), b1 = bf16rne(a[1]), b2 = bf16rne(a[2]), b3 = bf16rne(a[3]);
      int n = n0 + wn + j*16 + fr;
      int h = hb + wm + i*16 + fg*4;
      *(uint2*)&t1h[(size_t)img * HW + ((size_t)n << 9) + h] =
          make_uint2((b1<<16)|b0, (b3<<16)|b2);
    }
}

// ==== MFMA col pass: single-bf16 A (CmH), 64 KB LDS -> 2 blocks/CU; fused q-hist ====
__global__ __launch_bounds__(512, 4) void k_colpass(
    const unsigned short* __restrict__ t1h,
    const unsigned short* __restrict__ CmH,
    float* __restrict__ res, unsigned* __restrict__ qh)
{
  __shared__ __align__(16) unsigned short AsH[2][8192];
  __shared__ __align__(16) unsigned short Bs [2][8192];

  // XCD swizzle: all 16 blocks of one image on the same XCD (t1 image L2-resident)
  const int b    = blockIdx.x;           // 0..1535
  const int xcd  = b & 7;
  const int i8   = b >> 3;               // 0..191
  const int img  = xcd * 12 + (i8 >> 4);
  const int r16  = i8 & 15;
  const int hp0  = (r16 >> 2) * 128;
  const int w0   = (r16 & 3) * 128;

  const int t    = threadIdx.x;
  const int lane = t & 63;
  const int wv   = t >> 6;
  const int wm   = (wv >> 2) * 64;
  const int wn   = (wv & 3) * 32;
  const int fr   = lane & 15;
  const int fg   = lane >> 4;
  const int sw   = lane & 7;

  const int drow = lane >> 3;
  const int dblk = (lane & 7) ^ drow;
  const unsigned short* ahsrc = CmH + ((size_t)(hp0 + wv*8 + drow) << 9) + dblk * 8;
  const unsigned short* bsrc  = t1h + (size_t)img * HW + ((size_t)(w0 + wv*8 + drow) << 9) + dblk * 8;
  const int dbase = wv * 8 * 64;

  f32x4 acc[4][2];
  #pragma unroll
  for(int i = 0; i < 4; i++)
    #pragma unroll
    for(int j = 0; j < 2; j++) acc[i][j] = (f32x4){0.f, 0.f, 0.f, 0.f};

  auto STAGE = [&](int buf, int k0){
    #pragma unroll
    for(int q = 0; q < 2; q++){
      const size_t so = ((size_t)(q * 64) << 9) + k0;
      const int    dq = dbase + q * 4096;
      gll16(ahsrc + so, &AsH[buf][dq]);
      gll16(bsrc  + so, &Bs [buf][dq]);
    }
  };
  auto COMPUTE = [&](int buf){
    bf16x8 ah[4][2], bv[2][2];
    #pragma unroll
    for(int i = 0; i < 4; i++)
      #pragma unroll
      for(int kq = 0; kq < 2; kq++){
        int row = wm + i*16 + fr;
        ah[i][kq] = *(const bf16x8*)&AsH[buf][row*64 + (((kq*4 + fg) ^ sw) << 3)];
      }
    #pragma unroll
    for(int j = 0; j < 2; j++)
      #pragma unroll
      for(int kq = 0; kq < 2; kq++){
        int row = wn + j*16 + fr;
        bv[j][kq] = *(const bf16x8*)&Bs[buf][row*64 + (((kq*4 + fg) ^ sw) << 3)];
      }
    __builtin_amdgcn_s_setprio(1);
    #pragma unroll
    for(int i = 0; i < 4; i++)
      #pragma unroll
      for(int j = 0; j < 2; j++){
        acc[i][j] = __builtin_amdgcn_mfma_f32_16x16x32_bf16(ah[i][0], bv[j][0], acc[i][j], 0, 0, 0);
        acc[i][j] = __builtin_amdgcn_mfma_f32_16x16x32_bf16(ah[i][1], bv[j][1], acc[i][j], 0, 0, 0);
      }
    __builtin_amdgcn_s_setprio(0);
  };

  STAGE(0, 0);
  asm volatile("s_waitcnt vmcnt(0)" ::: "memory");
  __builtin_amdgcn_s_barrier();
  #pragma unroll
  for(int it = 0; it < 7; ++it){
    STAGE((it + 1) & 1, (it + 1) * 64);
    asm volatile("s_waitcnt vmcnt(4)" ::: "memory");   // drain tile it, keep it+1 in flight
    __builtin_amdgcn_s_barrier();
    COMPUTE(it & 1);
    asm volatile("" ::: "memory");
    __builtin_amdgcn_s_barrier();
  }
  asm volatile("s_waitcnt vmcnt(0)" ::: "memory");
  __builtin_amdgcn_s_barrier();
  COMPUTE(1);

  // epilogue: store |acc|, LDS histogram (reuse staging LDS), flush
  __syncthreads();
  unsigned* shh = (unsigned*)&AsH[0][0];   // 16 KB of 32 KB
  for(int i = t; i < NQBIN; i += 512) shh[i] = 0;
  __syncthreads();

  float* rimg = res + (size_t)img * HW;
  #pragma unroll
  for(int i = 0; i < 4; i++)
    #pragma unroll
    for(int j = 0; j < 2; j++){
      f32x4 a = acc[i][j];
      int w  = w0 + wn + j*16 + fr;
      int hp = hp0 + wm + i*16 + fg*4;
      #pragma unroll
      for(int r = 0; r < 4; r++){
        float v = fabsf(a[r]);
        rimg[((size_t)(hp + r) << 9) + w] = v;
        atomicAdd(&shh[min((int)(v * 256.f), NQBIN - 1)], 1u);
      }
    }
  __syncthreads();

  unsigned* hg = qh + (size_t)img * NQBIN;
  for(int i = t; i < NQBIN; i += 512){
    unsigned c = shh[i];
    if(c) atomicAdd(&hg[i], c);
  }
}

// ---- percentiles (linear interp at 3% / 97%) -> (lo, 1/(hi-lo)) ----
__global__ void k_pct(const unsigned* __restrict__ qh, float2* __restrict__ prm){
  int img = blockIdx.x, t = threadIdx.x;
  const unsigned* h = qh + (size_t)img * NQBIN;
  __shared__ unsigned sh[NQBIN];
  for(int i = t; i < NQBIN; i += 256) sh[i] = h[i];
  __syncthreads();
  if(t == 0){
    const unsigned targ[4] = {7864u, 7865u, 254278u, 254279u};
    float v[4]; unsigned cum = 0; int b = 0;
    for(int q = 0; q < 4; q++){
      while(cum + sh[b] <= targ[q]){ cum += sh[b]; ++b; }
      v[q] = (float)b * (1.0f / 256.0f);
    }
    double plo = 0.03 * 262143.0;
    double phi = 0.97 * 262143.0;
    float lo = v[0] + (float)(plo - 7864.0)   * (v[1] - v[0]);
    float hi = v[2] + (float)(phi - 254278.0) * (v[3] - v[2]);
    prm[img] = make_float2(lo, 1.0f / (hi - lo));
  }
}

// ---- in-place normalize: out = (res - lo) * inv * mask ----
__global__ __launch_bounds__(256) void k_norm(float* __restrict__ out, const float* __restrict__ mask,
                                              const float2* __restrict__ prm){
  size_t i4 = (size_t)blockIdx.x * blockDim.x + threadIdx.x;
  const size_t total4 = (size_t)NIMG * HW / 4;
  const size_t step = (size_t)gridDim.x * blockDim.x;
  for(; i4 < total4; i4 += step){
    size_t i = i4 * 4;
    int bc = (int)(i >> 18);
    int bb = bc / 3;
    size_t mi = ((size_t)bb << 18) + (i & 0x3FFFFu);
    float4 r = *(float4*)(out + i);
    float4 m = *(const float4*)(mask + mi);
    float2 p = prm[bc];
    float4 o;
    o.x = (r.x - p.x) * p.y * m.x;
    o.y = (r.y - p.x) * p.y * m.y;
    o.z = (r.z - p.x) * p.y * m.z;
    o.w = (r.w - p.x) * p.y * m.w;
    *(float4*)(out + i) = o;
  }
}

extern "C" void kernel_launch(void* const* d_in, const int* in_sizes, int n_in,
                              void* d_out, int out_size, void* d_ws, size_t ws_size,
                              hipStream_t stream)
{
  const float* x       = (const float*)d_in[0];
  const float* mask    = (const float*)d_in[1];
  const float* fmap_in = (const float*)d_in[2];
  float* out = (float*)d_out;

  const size_t T1_BYTES = (size_t)NIMG * HW * 2;   // 48 MiB (bf16 t1T)
  char* ws = (char*)d_ws;
  unsigned short* t1h = (unsigned short*)ws;                    // lives rowpass..colpass
  // aliases with non-overlapping lifetimes:
  unsigned* h1 = (unsigned*)ws;                                 // dead before rowpass writes t1h
  unsigned* h2 = (unsigned*)(ws + (size_t)NIMG * 4096 * 4);
  unsigned* qh = (unsigned*)(ws + T1_BYTES);                    // own region (1.5 MB)
  char* tail = ws + T1_BYTES + (size_t)NIMG * NQBIN * 4;
  float*          Dir = (float*)tail;                           // 2048 B
  unsigned short* CmH = (unsigned short*)(tail + 2048);         // 512 KB
  char* tail2 = tail + 2048 + 524288;
  float*  med  = (float*)tail2;
  uint2*  sel1 = (uint2*)(tail2 + 512);
  float2* prm  = (float2*)(tail2 + 1536);

  k_dir<<<512, 256, 0, stream>>>(fmap_in, Dir);
  k_cmat<<<512, 256, 0, stream>>>(Dir, CmH);

  // 2-pass LDS radix select: median prefix to 24 bits (midpoint, err <= 8e-6)
  hipMemsetAsync(h1, 0, (size_t)NIMG * 4096 * 4 * 2, stream);
  k_p1<<<NIMG * 8, 256, 0, stream>>>(x, h1);
  k_scan1<<<NIMG, 256, 0, stream>>>(h1, sel1);
  k_p2<<<NIMG * 8, 256, 0, stream>>>(x, sel1, h2);
  k_scan_med<<<NIMG, 256, 0, stream>>>(h2, sel1, med);

  hipMemsetAsync(qh, 0, (size_t)NIMG * NQBIN * 4, stream);
  k_rowpass<<<1536, 512, 0, stream>>>(x, mask, med, CmH, t1h);
  k_colpass<<<1536, 512, 0, stream>>>(t1h, CmH, out, qh);

  k_pct<<<NIMG, 256, 0, stream>>>(qh, prm);
  k_norm<<<2048, 256, 0, stream>>>(out, mask, prm);
}